// Round 12
// baseline (517.729 us; speedup 1.0000x reference)
//
#include <hip/hip_runtime.h>
#include <math.h>

typedef _Float16 f16;
typedef f16 f16x4 __attribute__((ext_vector_type(4)));
typedef f16 f16x8 __attribute__((ext_vector_type(8)));
typedef float f32x4 __attribute__((ext_vector_type(4)));

#define NB 4

// Transpose + convert conv weights: w[co][ci][9] f32 -> wt[k][co][ci] f16.
__global__ void __launch_bounds__(256)
wtrans_kernel(const float* __restrict__ w, f16* __restrict__ wt, int Co, int Cin) {
  int idx = blockIdx.x * 256 + threadIdx.x;
  int total = Co * Cin * 9;
  if (idx >= total) return;
  int ci = idx % Cin, t2 = idx / Cin;
  int co = t2 % Co, k = t2 / Co;
  wt[idx] = (f16)w[((size_t)co * Cin + ci) * 9 + k];
}

// NCHW f32 -> NHWC f16 (Cin=1024 inputs). Block: one (b,h) x 64-channel chunk.
__global__ void __launch_bounds__(256)
nchw2nhwc(const float* __restrict__ in, f16* __restrict__ out) {
  __shared__ f16 s[64][66];
  const int t = threadIdx.x;
  const int bh = blockIdx.x, c0 = blockIdx.y * 64;
  const int b = bh >> 6, h = bh & 63;
  const int w = t & 63, cr = t >> 6;
  #pragma unroll
  for (int i = 0; i < 16; ++i) {
    int c = c0 + cr * 16 + i;
    s[cr * 16 + i][w] = (f16)in[(((size_t)b * 1024 + c) * 64 + h) * 64 + w];
  }
  __syncthreads();
  #pragma unroll
  for (int i = 0; i < 2; ++i) {
    int task = t + 256 * i;
    int oct = task & 7, w2 = task >> 3;
    f16x8 v;
    #pragma unroll
    for (int j = 0; j < 8; ++j) v[j] = s[oct * 8 + j][w2];
    *(f16x8*)(out + (((size_t)b * 64 + h) * 64 + w2) * 1024 + c0 + oct * 8) = v;
  }
}

// Big conv (conv1/conv4): Cin=1024, Co=256, K-split 4, raw f32 accs -> pacc.
// 512 thr = 8 waves (2 co-halves x 4 px). Block tile: 128co x 8rows x 64w.
// Wave = 64co x 128px = 4(m) x 8(n) frags. LDS: xs[10][66][40] + ws[9][128][40]
// = 145 KB -> 1 block/CU but 8 waves = 2/SIMD (LDS pipe needs multi-wave).
__global__ void __launch_bounds__(512, 1)
conv_big(const f16* __restrict__ in, const f16* __restrict__ wt,
         float* __restrict__ pacc) {
  constexpr int Cin = 1024, Co = 256;
  __shared__ __align__(16) f16 xs[10][66][40];
  __shared__ __align__(16) f16 ws[9][128][40];

  const int t = threadIdx.x;
  const int tile = blockIdx.x;       // 32 = 4b x 8 row-groups
  const int b = tile >> 3;
  const int h0 = (tile & 7) * 8;
  const int co_blk = blockIdx.y * 128;
  const int ciBase = blockIdx.z * 256;
  const int wid = t >> 6, lane = t & 63;
  const int wave_co = wid >> 2, wave_px = wid & 3;
  const int l15 = lane & 15, lg = lane >> 4;
  const int koff = lg * 8;

  f32x4 acc[4][8];
  #pragma unroll
  for (int m = 0; m < 4; ++m)
    #pragma unroll
    for (int n = 0; n < 8; ++n)
      #pragma unroll
      for (int r = 0; r < 4; ++r) acc[m][n][r] = 0.f;

  const f16* inb = in + (size_t)b * Cin * 4096;
  f16x8 ireg[5], wreg[9];

  auto load_stage = [&](int ci0) {
    #pragma unroll
    for (int i = 0; i < 5; ++i) {    // 2560 = 10 rows x 64 w x 4 oct
      int task = t + 512 * i;
      int r = task >> 8, rem = task & 255;
      int w_ = rem >> 2, oct = rem & 3;
      int gh = h0 - 1 + r;
      f16x8 v = {};
      if ((unsigned)gh < 64u)
        v = *(const f16x8*)(inb + ((size_t)gh * 64 + w_) * Cin + ci0 + oct * 8);
      ireg[i] = v;
    }
    #pragma unroll
    for (int i = 0; i < 9; ++i) {    // 4608 = 9 tap x 128 co x 4 oct
      int s = t + 512 * i;
      int oct = s & 3, co = (s >> 2) & 127, k = s >> 9;
      wreg[i] = *(const f16x8*)(wt + ((size_t)k * Co + co_blk + co) * Cin + ci0 + oct * 8);
    }
  };
  auto write_stage = [&]() {
    #pragma unroll
    for (int i = 0; i < 5; ++i) {
      int task = t + 512 * i;
      int r = task >> 8, rem = task & 255;
      int w_ = rem >> 2, oct = rem & 3;
      *(f16x8*)&xs[r][w_ + 1][oct * 8] = ireg[i];
    }
    #pragma unroll
    for (int i = 0; i < 9; ++i) {
      int s = t + 512 * i;
      int oct = s & 3, co = (s >> 2) & 127, k = s >> 9;
      *(f16x8*)&ws[k][co][oct * 8] = wreg[i];
    }
  };

  if (t < 80) {                      // zero w-halo columns once
    int r = t >> 3, side = (t >> 2) & 1, oc = t & 3;
    f16x8 z = {};
    *(f16x8*)&xs[r][side * 65][oc * 8] = z;
  }
  load_stage(ciBase);
  write_stage();
  __syncthreads();

  for (int c = 0; c < 8; ++c) {
    if (c + 1 < 8) load_stage(ciBase + ((c + 1) << 5));
    #pragma unroll
    for (int tap = 0; tap < 9; ++tap) {
      const int dh = tap / 3 - 1, dw = tap % 3 - 1;
      f16x8 af[4];
      #pragma unroll
      for (int m = 0; m < 4; ++m)
        af[m] = *(const f16x8*)&ws[tap][wave_co * 64 + m * 16 + l15][koff];
      #pragma unroll
      for (int n = 0; n < 8; ++n) {
        const f16x8 bf = *(const f16x8*)&xs[wave_px * 2 + (n >> 2) + dh + 1]
                                          [(n & 3) * 16 + l15 + 1 + dw][koff];
        #pragma unroll
        for (int m = 0; m < 4; ++m)
          acc[m][n] = __builtin_amdgcn_mfma_f32_16x16x32_f16(af[m], bf, acc[m][n], 0, 0, 0);
      }
    }
    __syncthreads();
    if (c + 1 < 8) write_stage();
    __syncthreads();
  }

  float* pb = pacc + (size_t)blockIdx.z * 16384 * Co + (size_t)b * 4096 * Co;
  #pragma unroll
  for (int m = 0; m < 4; ++m)
    #pragma unroll
    for (int n = 0; n < 8; ++n) {
      int px = (h0 + wave_px * 2 + (n >> 2)) * 64 + (n & 3) * 16 + l15;
      int co = co_blk + wave_co * 64 + m * 16 + lg * 4;
      *(f32x4*)(pb + (size_t)px * Co + co) = acc[m][n];
    }
}

// Implicit-GEMM 3x3 conv + BN + ReLU (mid-size convs), 256 thr, RPW=1.
// Wave = 64co x 64px = 4x4 frags; block = 64co x 4 rows. kspl via blockIdx.z:
// pacc!=null -> raw accs (linear, exact). out!=null -> BN+ReLU f16 NHWC.
// Neither -> pooled partials (conv5, kspl MUST be 1: BN+ReLU nonlinear).
__global__ void __launch_bounds__(256, 1)
conv_mfma(const f16* __restrict__ in, const f16* __restrict__ in2,
          const f16* __restrict__ wt, const float* __restrict__ bn,
          f16* __restrict__ out, float* __restrict__ pacc,
          float* __restrict__ partial, int Cin, int Co, int kspl) {
  __shared__ __align__(16) f16 xs[6][66][40];
  __shared__ __align__(16) f16 ws[9][64][40];
  __shared__ float s_red[4][64];

  const int t = threadIdx.x;
  const int tile = blockIdx.x;       // 64 = 4b x 16 row-quads
  const int b = tile >> 4;
  const int h0 = (tile & 15) * 4;
  const int co_blk = blockIdx.y * 64;
  const int ciBase = blockIdx.z * (Cin / kspl);
  const int NC = (Cin / kspl) >> 5;
  const int wid = t >> 6, lane = t & 63;
  const int l15 = lane & 15, lg = lane >> 4;
  const int koff = lg * 8;

  f32x4 acc[4][4];
  #pragma unroll
  for (int m = 0; m < 4; ++m)
    #pragma unroll
    for (int n = 0; n < 4; ++n)
      #pragma unroll
      for (int r = 0; r < 4; ++r) acc[m][n][r] = 0.f;

  const f16* inb = in + (size_t)b * Cin * 4096;
  const f16* inb2 = in2 ? in2 + (size_t)b * Cin * 4096 : nullptr;

  const int wS = t >> 2, octS = t & 3;
  f16x8 ireg[6], wreg[9];

  auto load_stage = [&](int ci0) {
    #pragma unroll
    for (int r = 0; r < 6; ++r) {
      int gh = h0 - 1 + r;
      f16x8 v = {};
      if ((unsigned)gh < 64u) {
        size_t off = ((size_t)gh * 64 + wS) * Cin + ci0 + octS * 8;
        v = *(const f16x8*)(inb + off);
        if (inb2) { f16x8 v2 = *(const f16x8*)(inb2 + off); v = v - v2; }
      }
      ireg[r] = v;
    }
    #pragma unroll
    for (int i = 0; i < 9; ++i) {
      int s = t + 256 * i;
      int oct = s & 3, co = (s >> 2) & 63, k = s >> 8;
      wreg[i] = *(const f16x8*)(wt + ((size_t)k * Co + co_blk + co) * Cin + ci0 + oct * 8);
    }
  };
  auto write_stage = [&]() {
    #pragma unroll
    for (int r = 0; r < 6; ++r)
      *(f16x8*)&xs[r][wS + 1][octS * 8] = ireg[r];
    #pragma unroll
    for (int i = 0; i < 9; ++i) {
      int s = t + 256 * i;
      int oct = s & 3, co = (s >> 2) & 63, k = s >> 8;
      *(f16x8*)&ws[k][co][oct * 8] = wreg[i];
    }
  };

  if (t < 48) {
    int r = t >> 3, side = (t >> 2) & 1, oc = t & 3;
    f16x8 z = {};
    *(f16x8*)&xs[r][side * 65][oc * 8] = z;
  }
  load_stage(ciBase);
  write_stage();
  __syncthreads();

  for (int c = 0; c < NC; ++c) {
    if (c + 1 < NC) load_stage(ciBase + ((c + 1) << 5));
    #pragma unroll
    for (int tap = 0; tap < 9; ++tap) {
      const int dh = tap / 3 - 1, dw = tap % 3 - 1;
      f16x8 af[4];
      #pragma unroll
      for (int m = 0; m < 4; ++m)
        af[m] = *(const f16x8*)&ws[tap][m * 16 + l15][koff];
      #pragma unroll
      for (int n = 0; n < 4; ++n) {
        const f16x8 bf = *(const f16x8*)&xs[wid + dh + 1][n * 16 + l15 + 1 + dw][koff];
        #pragma unroll
        for (int m = 0; m < 4; ++m)
          acc[m][n] = __builtin_amdgcn_mfma_f32_16x16x32_f16(af[m], bf, acc[m][n], 0, 0, 0);
      }
    }
    __syncthreads();
    if (c + 1 < NC) write_stage();
    __syncthreads();
  }

  if (pacc) {
    float* pb = pacc + (size_t)blockIdx.z * 16384 * Co + (size_t)b * 4096 * Co;
    #pragma unroll
    for (int m = 0; m < 4; ++m)
      #pragma unroll
      for (int n = 0; n < 4; ++n) {
        int px = (h0 + wid) * 64 + n * 16 + l15;
        *(f32x4*)(pb + (size_t)px * Co + co_blk + m * 16 + lg * 4) = acc[m][n];
      }
  } else if (out) {
    #pragma unroll
    for (int m = 0; m < 4; ++m) {
      float sc[4], sh[4];
      #pragma unroll
      for (int reg = 0; reg < 4; ++reg) {
        int co = co_blk + m * 16 + lg * 4 + reg;
        sc[reg] = bn[co] / sqrtf(bn[3 * Co + co] + 1e-5f);
        sh[reg] = bn[Co + co] - bn[2 * Co + co] * sc[reg];
      }
      #pragma unroll
      for (int n = 0; n < 4; ++n) {
        f16x4 v;
        #pragma unroll
        for (int reg = 0; reg < 4; ++reg)
          v[reg] = (f16)fmaxf(fmaf(acc[m][n][reg], sc[reg], sh[reg]), 0.f);
        *(f16x4*)(out + ((size_t)(b * 64 + h0 + wid) * 64 + n * 16 + l15) * Co
                      + co_blk + m * 16 + lg * 4) = v;
      }
    }
  } else {
    #pragma unroll
    for (int m = 0; m < 4; ++m)
      #pragma unroll
      for (int reg = 0; reg < 4; ++reg) {
        int co = co_blk + m * 16 + lg * 4 + reg;
        float sc = bn[co] / sqrtf(bn[3 * Co + co] + 1e-5f);
        float sh = bn[Co + co] - bn[2 * Co + co] * sc;
        float s = 0.f;
        #pragma unroll
        for (int n = 0; n < 4; ++n)
          s += fmaxf(fmaf(acc[m][n][reg], sc, sh), 0.f);
        s += __shfl_xor(s, 1, 64);
        s += __shfl_xor(s, 2, 64);
        s += __shfl_xor(s, 4, 64);
        s += __shfl_xor(s, 8, 64);
        if (l15 == 0) s_red[wid][m * 16 + lg * 4 + reg] = s;
      }
    __syncthreads();
    if (t < 64) {
      float v = s_red[0][t] + s_red[1][t] + s_red[2][t] + s_red[3][t];
      partial[((size_t)b * Co + co_blk + t) * 16 + (tile & 15)] = v;
    }
  }
}

// Sum nslab K-slices + BN + ReLU -> NHWC f16. Grid: 4*Co blocks.
__global__ void __launch_bounds__(256)
kreduce(const float* __restrict__ pacc, const float* __restrict__ bn,
        f16* __restrict__ out, int Co, int nslab) {
  const int t = threadIdx.x;
  const size_t slab = (size_t)16384 * Co;
  const int cq = t % (Co >> 2);
  float sc[4], sh[4];
  #pragma unroll
  for (int r = 0; r < 4; ++r) {
    int co = cq * 4 + r;
    sc[r] = bn[co] / sqrtf(bn[3 * Co + co] + 1e-5f);
    sh[r] = bn[Co + co] - bn[2 * Co + co] * sc[r];
  }
  #pragma unroll
  for (int i = 0; i < 4; ++i) {
    size_t idx = (size_t)blockIdx.x * 1024 + i * 256 + t;
    f32x4 a = *(const f32x4*)(pacc + idx * 4);
    for (int s = 1; s < nslab; ++s) {
      f32x4 b2 = *(const f32x4*)(pacc + slab * s + idx * 4);
      #pragma unroll
      for (int r = 0; r < 4; ++r) a[r] += b2[r];
    }
    f16x4 v;
    #pragma unroll
    for (int r = 0; r < 4; ++r)
      v[r] = (f16)fmaxf(fmaf(a[r], sc[r], sh[r]), 0.f);
    *(f16x4*)(out + idx * 4) = v;
  }
}

// out[b,h,w,c] = sum_k atten[b,h,w,k] * x[b,h+dh,w+dw,c], NHWC f16, C=64.
__global__ void __launch_bounds__(256)
weighting_nhwc(const f16* __restrict__ x, const float* __restrict__ atten,
               f16* __restrict__ out) {
  __shared__ float s_a[64 * 81];
  const int h = blockIdx.x, b = blockIdx.y;
  const int t = threadIdx.x;
  for (int idx = t; idx < 64 * 81; idx += 256)
    s_a[idx] = atten[(size_t)((b * 64 + h) * 64) * 81 + idx];
  __syncthreads();

  const int w = t & 63, cg = t >> 6;
  float acc[16];
  #pragma unroll
  for (int j = 0; j < 16; ++j) acc[j] = 0.f;

  for (int dh = -4; dh <= 4; ++dh) {
    int hh = h + dh;
    if ((unsigned)hh >= 64u) continue;
    #pragma unroll
    for (int dw = -4; dw <= 4; ++dw) {
      int ww = w + dw;
      if ((unsigned)ww >= 64u) continue;
      float a = s_a[w * 81 + (dh + 4) * 9 + (dw + 4)];
      const f16* xp = x + (((size_t)b * 64 + hh) * 64 + ww) * 64 + cg * 16;
      f16x8 v0 = *(const f16x8*)xp;
      f16x8 v1 = *(const f16x8*)(xp + 8);
      #pragma unroll
      for (int j = 0; j < 8; ++j) {
        acc[j]     = fmaf(a, (float)v0[j], acc[j]);
        acc[8 + j] = fmaf(a, (float)v1[j], acc[8 + j]);
      }
    }
  }
  f16x8 o0, o1;
  #pragma unroll
  for (int j = 0; j < 8; ++j) { o0[j] = (f16)acc[j]; o1[j] = (f16)acc[8 + j]; }
  f16* op = out + (((size_t)b * 64 + h) * 64 + w) * 64 + cg * 16;
  *(f16x8*)op = o0;
  *(f16x8*)(op + 8) = o1;
}

// partial[4][256][16] -> mean -> FC 256->10 -> 1. One block, wave per b.
__global__ void __launch_bounds__(256)
fc_kernel(const float* __restrict__ partial, const float* __restrict__ fw1,
          const float* __restrict__ fb1, const float* __restrict__ fw2,
          const float* __restrict__ fb2, float* __restrict__ outp) {
  const int t = threadIdx.x;
  const int b = t >> 6, lane = t & 63;
  float pooled[4];
  #pragma unroll
  for (int k = 0; k < 4; ++k) {
    int c = lane + 64 * k;
    float s = 0.f;
    #pragma unroll
    for (int p = 0; p < 16; ++p) s += partial[(size_t)(b * 256 + c) * 16 + p];
    pooled[k] = s * (1.f / 4096.f);
  }
  float o = 0.f;
  for (int i = 0; i < 10; ++i) {
    float d = 0.f;
    #pragma unroll
    for (int k = 0; k < 4; ++k) d += pooled[k] * fw1[i * 256 + lane + 64 * k];
    #pragma unroll
    for (int off = 32; off > 0; off >>= 1) d += __shfl_down(d, off, 64);
    o += (d + fb1[i]) * fw2[i];
  }
  if (lane == 0) outp[b] = o + fb2[0];
}

extern "C" void kernel_launch(void* const* d_in, const int* in_sizes, int n_in,
                              void* d_out, int out_size, void* d_ws, size_t ws_size,
                              hipStream_t stream) {
  const float* low_key    = (const float*)d_in[0];
  const float* low_nonkey = (const float*)d_in[1];
  const float* atten      = (const float*)d_in[2];
  const float* w1 = (const float*)d_in[3];  const float* bn1 = (const float*)d_in[4];
  const float* w2 = (const float*)d_in[5];  const float* bn2 = (const float*)d_in[6];
  const float* w3 = (const float*)d_in[7];  const float* bn3 = (const float*)d_in[8];
  const float* w4 = (const float*)d_in[9];  const float* bn4 = (const float*)d_in[10];
  const float* w5 = (const float*)d_in[11]; const float* bn5 = (const float*)d_in[12];
  const float* fw1 = (const float*)d_in[13]; const float* fb1 = (const float*)d_in[14];
  const float* fw2 = (const float*)d_in[15]; const float* fb2 = (const float*)d_in[16];

  // Layout (f16 units unless noted). Pacc (67.1 MB) aliases the dead X2/X3
  // region: X2/X3 only live between kreduce1..conv3, Pacc only during
  // conv_big/conv2 dispatches. kreduce outputs (X1, Y, X2) are outside the
  // region they read.
  f16* T   = (f16*)d_ws;               // 16,777,216
  f16* X1  = T + 16777216;             // 4,194,304
  f16* Y   = X1 + 4194304;             // 4,194,304
  f16* wt1 = Y + 4194304;              // 2,359,296
  f16* wt2 = wt1 + 2359296;            // 147,456
  f16* wt3 = wt2 + 147456;             // 147,456
  f16* wt4 = wt3 + 147456;             // 2,359,296
  f16* wt5 = wt4 + 2359296;            // 589,824
  float* P  = (float*)(wt5 + 589824);  // 16,384 f32
  f16* X2   = (f16*)(P + 16384);       // 1,048,576
  f16* X3   = X2 + 1048576;            // 1,048,576
  float* Pacc  = (float*)X2;           // 4 slabs x 4,194,304 f32 (aliases X2/X3+)
  float* Pacc2 = Pacc + 4194304;       // conv2 slabs (4 x 1,048,576 f32), disjoint from X2

  dim3 blk(256);
  wtrans_kernel<<<(256 * 1024 * 9 + 255) / 256, blk, 0, stream>>>(w1, wt1, 256, 1024);
  wtrans_kernel<<<(64 * 256 * 9 + 255) / 256, blk, 0, stream>>>(w2, wt2, 64, 256);
  wtrans_kernel<<<(256 * 64 * 9 + 255) / 256, blk, 0, stream>>>(w3, wt3, 256, 64);
  wtrans_kernel<<<(256 * 1024 * 9 + 255) / 256, blk, 0, stream>>>(w4, wt4, 256, 1024);
  wtrans_kernel<<<(256 * 256 * 9 + 255) / 256, blk, 0, stream>>>(w5, wt5, 256, 256);

  // lk -> NHWC f16
  nchw2nhwc<<<dim3(256, 16), blk, 0, stream>>>(low_key, T);
  // x1 = cbr(lk, w1): 512-thr big conv, K-split 4 -> Pacc -> kreduce
  conv_big<<<dim3(32, 2, 4), dim3(512), 0, stream>>>(T, wt1, Pacc);
  kreduce<<<1024, blk, 0, stream>>>(Pacc, bn1, X1, 256, 4);
  // x2 = cbr(x1, w2): K-split 4 (grid 64 -> 256 blocks) -> Pacc2 -> kreduce
  conv_mfma<<<dim3(64, 1, 4), blk, 0, stream>>>(X1, nullptr, wt2, bn2, nullptr, Pacc2, nullptr, 256, 64, 4);
  kreduce<<<256, blk, 0, stream>>>(Pacc2, bn2, X2, 64, 4);
  // x3 = weighting(x2)
  weighting_nhwc<<<dim3(64, NB), blk, 0, stream>>>(X2, atten, X3);
  // x4 = cbr(x3, w3)   (reuses X1)
  conv_mfma<<<dim3(64, 4, 1), blk, 0, stream>>>(X3, nullptr, wt3, bn3, X1, nullptr, nullptr, 64, 256, 1);
  // lnk -> NHWC f16 (T free)
  nchw2nhwc<<<dim3(256, 16), blk, 0, stream>>>(low_nonkey, T);
  // y = cbr(lnk, w4): big conv (X2/X3 dead -> Pacc reusable)
  conv_big<<<dim3(32, 2, 4), dim3(512), 0, stream>>>(T, wt4, Pacc);
  kreduce<<<1024, blk, 0, stream>>>(Pacc, bn4, Y, 256, 4);
  // z = cbr(x4 - y, w5) -> pooled partials (NO K-split: BN+ReLU nonlinear)
  conv_mfma<<<dim3(64, 4, 1), blk, 0, stream>>>(X1, Y, wt5, bn5, nullptr, nullptr, P, 256, 256, 1);
  // mean -> FC -> FC
  fc_kernel<<<1, 256, 0, stream>>>(P, fw1, fb1, fw2, fb2, (float*)d_out);
}

// Round 13
// 407.115 us; speedup vs baseline: 1.2717x; 1.2717x over previous
//
#include <hip/hip_runtime.h>
#include <math.h>

typedef _Float16 f16;
typedef f16 f16x4 __attribute__((ext_vector_type(4)));
typedef f16 f16x8 __attribute__((ext_vector_type(8)));
typedef float f32x4 __attribute__((ext_vector_type(4)));

#define NB 4

// Transpose + convert conv weights: w[co][ci][9] f32 -> wt[k][co][ci] f16.
__global__ void __launch_bounds__(256)
wtrans_kernel(const float* __restrict__ w, f16* __restrict__ wt, int Co, int Cin) {
  int idx = blockIdx.x * 256 + threadIdx.x;
  int total = Co * Cin * 9;
  if (idx >= total) return;
  int ci = idx % Cin, t2 = idx / Cin;
  int co = t2 % Co, k = t2 / Co;
  wt[idx] = (f16)w[((size_t)co * Cin + ci) * 9 + k];
}

// NCHW f32 -> NHWC f16 (Cin=1024 inputs). Block: one (b,h) x 64-channel chunk.
__global__ void __launch_bounds__(256)
nchw2nhwc(const float* __restrict__ in, f16* __restrict__ out) {
  __shared__ f16 s[64][66];
  const int t = threadIdx.x;
  const int bh = blockIdx.x, c0 = blockIdx.y * 64;
  const int b = bh >> 6, h = bh & 63;
  const int w = t & 63, cr = t >> 6;
  #pragma unroll
  for (int i = 0; i < 16; ++i) {
    int c = c0 + cr * 16 + i;
    s[cr * 16 + i][w] = (f16)in[(((size_t)b * 1024 + c) * 64 + h) * 64 + w];
  }
  __syncthreads();
  #pragma unroll
  for (int i = 0; i < 2; ++i) {
    int task = t + 256 * i;
    int oct = task & 7, w2 = task >> 3;
    f16x8 v;
    #pragma unroll
    for (int j = 0; j < 8; ++j) v[j] = s[oct * 8 + j][w2];
    *(f16x8*)(out + (((size_t)b * 64 + h) * 64 + w2) * 1024 + c0 + oct * 8) = v;
  }
}

// conv1/conv4 (Cin=1024, Co=256): A-from-global + B-from-LDS implicit GEMM.
// 256 thr = 4 waves, each wave = ONE 64-co group x 128 px (4m x 8n frags).
// Block = 256co x 2 rows -> input staged ONCE for all 256 co (xs 21 KB only).
// A-frags stream from wt[tap][co][ci] (per-z slab 1.18 MB = L2-resident,
// co-identical across the 2 blocks/CU -> L1 dedup) with 2-buffer per-tap
// register prefetch. K-split 4 (blockIdx.z) -> raw f32 accs to pacc (linear).
__global__ void __launch_bounds__(256, 2)
conv_bigK(const f16* __restrict__ in, const f16* __restrict__ wt,
          float* __restrict__ pacc) {
  constexpr int Cin = 1024, Co = 256, NC = 8;
  __shared__ __align__(16) f16 xs[4][66][40];

  const int t = threadIdx.x;
  const int tile = blockIdx.x;       // 128 = 4b x 32 row-pairs
  const int b = tile >> 5;
  const int h0 = (tile & 31) * 2;
  const int ciBase = blockIdx.z * 256;
  const int wid = t >> 6, lane = t & 63;
  const int l15 = lane & 15, lg = lane >> 4;
  const int koff = lg * 8;

  f32x4 acc[4][8];
  #pragma unroll
  for (int m = 0; m < 4; ++m)
    #pragma unroll
    for (int n = 0; n < 8; ++n)
      #pragma unroll
      for (int r = 0; r < 4; ++r) acc[m][n][r] = 0.f;

  const f16* inb = in + (size_t)b * Cin * 4096;
  const int wS = t >> 2, octS = t & 3;
  f16x8 ireg[4];

  auto load_stage = [&](int c) {
    int ci0 = ciBase + c * 32;
    #pragma unroll
    for (int r = 0; r < 4; ++r) {
      int gh = h0 - 1 + r;
      f16x8 v = {};
      if ((unsigned)gh < 64u)
        v = *(const f16x8*)(inb + ((size_t)gh * 64 + wS) * Cin + ci0 + octS * 8);
      ireg[r] = v;
    }
  };
  auto write_stage = [&]() {
    #pragma unroll
    for (int r = 0; r < 4; ++r)
      *(f16x8*)&xs[r][wS + 1][octS * 8] = ireg[r];
  };

  // A-fragment base offset for this thread (per m add m*16*Cin; per tap add tap*Co*Cin)
  const f16* wA = wt + (size_t)(wid * 64 + l15) * Cin + koff + ciBase;

  f16x8 afA[4], afB[4];
  #pragma unroll
  for (int m = 0; m < 4; ++m)        // prologue: A(c=0, tap=0)
    afA[m] = *(const f16x8*)(wA + (size_t)m * 16 * Cin);

  if (t < 32) {                      // zero w-halo columns once
    int r = t >> 3, side = (t >> 2) & 1, oc = t & 3;
    f16x8 z = {};
    *(f16x8*)&xs[r][side * 65][oc * 8] = z;
  }
  load_stage(0);
  write_stage();
  __syncthreads();

  for (int c = 0; c < NC; ++c) {
    if (c + 1 < NC) load_stage(c + 1);   // input globals fly during MFMA phase
    #pragma unroll
    for (int tap = 0; tap < 9; ++tap) {
      const int dh = tap / 3 - 1, dw = tap % 3 - 1;
      // prefetch next tap's A into the other buffer (static parity select)
      const int nt = (tap < 8) ? tap + 1 : 0;
      const int ncc = (tap < 8) ? c : c + 1;
      const bool doPf = (tap < 8) || (c + 1 < NC);
      if ((tap & 1) == 0) {
        if (doPf)
          #pragma unroll
          for (int m = 0; m < 4; ++m)
            afB[m] = *(const f16x8*)(wA + ((size_t)nt * Co + m * 16) * Cin + ncc * 32);
        #pragma unroll
        for (int n = 0; n < 8; ++n) {
          const f16x8 bf = *(const f16x8*)&xs[(n >> 2) + dh + 1][(n & 3) * 16 + l15 + 1 + dw][koff];
          #pragma unroll
          for (int m = 0; m < 4; ++m)
            acc[m][n] = __builtin_amdgcn_mfma_f32_16x16x32_f16(afA[m], bf, acc[m][n], 0, 0, 0);
        }
      } else {
        if (doPf)
          #pragma unroll
          for (int m = 0; m < 4; ++m)
            afA[m] = *(const f16x8*)(wA + ((size_t)nt * Co + m * 16) * Cin + ncc * 32);
        #pragma unroll
        for (int n = 0; n < 8; ++n) {
          const f16x8 bf = *(const f16x8*)&xs[(n >> 2) + dh + 1][(n & 3) * 16 + l15 + 1 + dw][koff];
          #pragma unroll
          for (int m = 0; m < 4; ++m)
            acc[m][n] = __builtin_amdgcn_mfma_f32_16x16x32_f16(afB[m], bf, acc[m][n], 0, 0, 0);
        }
      }
    }
    // tap8 (even) prefetched (c+1, tap0) into afB -> roll it into afA
    #pragma unroll
    for (int m = 0; m < 4; ++m) afA[m] = afB[m];
    __syncthreads();                  // all xs reads of chunk c done
    if (c + 1 < NC) write_stage();
    __syncthreads();                  // chunk c+1 visible
  }

  // raw f32 accs -> pacc[z][b][px][co] (kreduce applies BN+ReLU after sum)
  float* pb = pacc + (size_t)blockIdx.z * 4194304 + (size_t)b * 4096 * Co;
  #pragma unroll
  for (int m = 0; m < 4; ++m)
    #pragma unroll
    for (int n = 0; n < 8; ++n) {
      int px = (h0 + (n >> 2)) * 64 + (n & 3) * 16 + l15;
      *(f32x4*)(pb + (size_t)px * Co + wid * 64 + m * 16 + lg * 4) = acc[m][n];
    }
}

// Mid-size convs (conv2/3/5): both operands in LDS, wave 64co x 64px (4x4).
// kspl via blockIdx.z: pacc!=null -> raw accs (linear). out!=null -> BN+ReLU
// f16 NHWC. Neither -> pooled partials (conv5, kspl MUST be 1: nonlinear).
__global__ void __launch_bounds__(256, 1)
conv_mfma(const f16* __restrict__ in, const f16* __restrict__ in2,
          const f16* __restrict__ wt, const float* __restrict__ bn,
          f16* __restrict__ out, float* __restrict__ pacc,
          float* __restrict__ partial, int Cin, int Co, int kspl) {
  __shared__ __align__(16) f16 xs[6][66][40];
  __shared__ __align__(16) f16 ws[9][64][40];
  __shared__ float s_red[4][64];

  const int t = threadIdx.x;
  const int tile = blockIdx.x;       // 64 = 4b x 16 row-quads
  const int b = tile >> 4;
  const int h0 = (tile & 15) * 4;
  const int co_blk = blockIdx.y * 64;
  const int ciBase = blockIdx.z * (Cin / kspl);
  const int NC = (Cin / kspl) >> 5;
  const int wid = t >> 6, lane = t & 63;
  const int l15 = lane & 15, lg = lane >> 4;
  const int koff = lg * 8;

  f32x4 acc[4][4];
  #pragma unroll
  for (int m = 0; m < 4; ++m)
    #pragma unroll
    for (int n = 0; n < 4; ++n)
      #pragma unroll
      for (int r = 0; r < 4; ++r) acc[m][n][r] = 0.f;

  const f16* inb = in + (size_t)b * Cin * 4096;
  const f16* inb2 = in2 ? in2 + (size_t)b * Cin * 4096 : nullptr;

  const int wS = t >> 2, octS = t & 3;
  f16x8 ireg[6], wreg[9];

  auto load_stage = [&](int ci0) {
    #pragma unroll
    for (int r = 0; r < 6; ++r) {
      int gh = h0 - 1 + r;
      f16x8 v = {};
      if ((unsigned)gh < 64u) {
        size_t off = ((size_t)gh * 64 + wS) * Cin + ci0 + octS * 8;
        v = *(const f16x8*)(inb + off);
        if (inb2) { f16x8 v2 = *(const f16x8*)(inb2 + off); v = v - v2; }
      }
      ireg[r] = v;
    }
    #pragma unroll
    for (int i = 0; i < 9; ++i) {
      int s = t + 256 * i;
      int oct = s & 3, co = (s >> 2) & 63, k = s >> 8;
      wreg[i] = *(const f16x8*)(wt + ((size_t)k * Co + co_blk + co) * Cin + ci0 + oct * 8);
    }
  };
  auto write_stage = [&]() {
    #pragma unroll
    for (int r = 0; r < 6; ++r)
      *(f16x8*)&xs[r][wS + 1][octS * 8] = ireg[r];
    #pragma unroll
    for (int i = 0; i < 9; ++i) {
      int s = t + 256 * i;
      int oct = s & 3, co = (s >> 2) & 63, k = s >> 8;
      *(f16x8*)&ws[k][co][oct * 8] = wreg[i];
    }
  };

  if (t < 48) {
    int r = t >> 3, side = (t >> 2) & 1, oc = t & 3;
    f16x8 z = {};
    *(f16x8*)&xs[r][side * 65][oc * 8] = z;
  }
  load_stage(ciBase);
  write_stage();
  __syncthreads();

  for (int c = 0; c < NC; ++c) {
    if (c + 1 < NC) load_stage(ciBase + ((c + 1) << 5));
    #pragma unroll
    for (int tap = 0; tap < 9; ++tap) {
      const int dh = tap / 3 - 1, dw = tap % 3 - 1;
      f16x8 af[4];
      #pragma unroll
      for (int m = 0; m < 4; ++m)
        af[m] = *(const f16x8*)&ws[tap][m * 16 + l15][koff];
      #pragma unroll
      for (int n = 0; n < 4; ++n) {
        const f16x8 bf = *(const f16x8*)&xs[wid + dh + 1][n * 16 + l15 + 1 + dw][koff];
        #pragma unroll
        for (int m = 0; m < 4; ++m)
          acc[m][n] = __builtin_amdgcn_mfma_f32_16x16x32_f16(af[m], bf, acc[m][n], 0, 0, 0);
      }
    }
    __syncthreads();
    if (c + 1 < NC) write_stage();
    __syncthreads();
  }

  if (pacc) {
    float* pb = pacc + (size_t)blockIdx.z * 16384 * Co + (size_t)b * 4096 * Co;
    #pragma unroll
    for (int m = 0; m < 4; ++m)
      #pragma unroll
      for (int n = 0; n < 4; ++n) {
        int px = (h0 + wid) * 64 + n * 16 + l15;
        *(f32x4*)(pb + (size_t)px * Co + co_blk + m * 16 + lg * 4) = acc[m][n];
      }
  } else if (out) {
    #pragma unroll
    for (int m = 0; m < 4; ++m) {
      float sc[4], sh[4];
      #pragma unroll
      for (int reg = 0; reg < 4; ++reg) {
        int co = co_blk + m * 16 + lg * 4 + reg;
        sc[reg] = bn[co] / sqrtf(bn[3 * Co + co] + 1e-5f);
        sh[reg] = bn[Co + co] - bn[2 * Co + co] * sc[reg];
      }
      #pragma unroll
      for (int n = 0; n < 4; ++n) {
        f16x4 v;
        #pragma unroll
        for (int reg = 0; reg < 4; ++reg)
          v[reg] = (f16)fmaxf(fmaf(acc[m][n][reg], sc[reg], sh[reg]), 0.f);
        *(f16x4*)(out + ((size_t)(b * 64 + h0 + wid) * 64 + n * 16 + l15) * Co
                      + co_blk + m * 16 + lg * 4) = v;
      }
    }
  } else {
    #pragma unroll
    for (int m = 0; m < 4; ++m)
      #pragma unroll
      for (int reg = 0; reg < 4; ++reg) {
        int co = co_blk + m * 16 + lg * 4 + reg;
        float sc = bn[co] / sqrtf(bn[3 * Co + co] + 1e-5f);
        float sh = bn[Co + co] - bn[2 * Co + co] * sc;
        float s = 0.f;
        #pragma unroll
        for (int n = 0; n < 4; ++n)
          s += fmaxf(fmaf(acc[m][n][reg], sc, sh), 0.f);
        s += __shfl_xor(s, 1, 64);
        s += __shfl_xor(s, 2, 64);
        s += __shfl_xor(s, 4, 64);
        s += __shfl_xor(s, 8, 64);
        if (l15 == 0) s_red[wid][m * 16 + lg * 4 + reg] = s;
      }
    __syncthreads();
    if (t < 64) {
      float v = s_red[0][t] + s_red[1][t] + s_red[2][t] + s_red[3][t];
      partial[((size_t)b * Co + co_blk + t) * 16 + (tile & 15)] = v;
    }
  }
}

// Sum nslab K-slices + BN + ReLU -> NHWC f16. Grid: 4*Co blocks.
__global__ void __launch_bounds__(256)
kreduce(const float* __restrict__ pacc, const float* __restrict__ bn,
        f16* __restrict__ out, int Co, int nslab) {
  const int t = threadIdx.x;
  const size_t slab = (size_t)16384 * Co;
  const int cq = t % (Co >> 2);
  float sc[4], sh[4];
  #pragma unroll
  for (int r = 0; r < 4; ++r) {
    int co = cq * 4 + r;
    sc[r] = bn[co] / sqrtf(bn[3 * Co + co] + 1e-5f);
    sh[r] = bn[Co + co] - bn[2 * Co + co] * sc[r];
  }
  #pragma unroll
  for (int i = 0; i < 4; ++i) {
    size_t idx = (size_t)blockIdx.x * 1024 + i * 256 + t;
    f32x4 a = *(const f32x4*)(pacc + idx * 4);
    for (int s = 1; s < nslab; ++s) {
      f32x4 b2 = *(const f32x4*)(pacc + slab * s + idx * 4);
      #pragma unroll
      for (int r = 0; r < 4; ++r) a[r] += b2[r];
    }
    f16x4 v;
    #pragma unroll
    for (int r = 0; r < 4; ++r)
      v[r] = (f16)fmaxf(fmaf(a[r], sc[r], sh[r]), 0.f);
    *(f16x4*)(out + idx * 4) = v;
  }
}

// out[b,h,w,c] = sum_k atten[b,h,w,k] * x[b,h+dh,w+dw,c], NHWC f16, C=64.
__global__ void __launch_bounds__(256)
weighting_nhwc(const f16* __restrict__ x, const float* __restrict__ atten,
               f16* __restrict__ out) {
  __shared__ float s_a[64 * 81];
  const int h = blockIdx.x, b = blockIdx.y;
  const int t = threadIdx.x;
  for (int idx = t; idx < 64 * 81; idx += 256)
    s_a[idx] = atten[(size_t)((b * 64 + h) * 64) * 81 + idx];
  __syncthreads();

  const int w = t & 63, cg = t >> 6;
  float acc[16];
  #pragma unroll
  for (int j = 0; j < 16; ++j) acc[j] = 0.f;

  for (int dh = -4; dh <= 4; ++dh) {
    int hh = h + dh;
    if ((unsigned)hh >= 64u) continue;
    #pragma unroll
    for (int dw = -4; dw <= 4; ++dw) {
      int ww = w + dw;
      if ((unsigned)ww >= 64u) continue;
      float a = s_a[w * 81 + (dh + 4) * 9 + (dw + 4)];
      const f16* xp = x + (((size_t)b * 64 + hh) * 64 + ww) * 64 + cg * 16;
      f16x8 v0 = *(const f16x8*)xp;
      f16x8 v1 = *(const f16x8*)(xp + 8);
      #pragma unroll
      for (int j = 0; j < 8; ++j) {
        acc[j]     = fmaf(a, (float)v0[j], acc[j]);
        acc[8 + j] = fmaf(a, (float)v1[j], acc[8 + j]);
      }
    }
  }
  f16x8 o0, o1;
  #pragma unroll
  for (int j = 0; j < 8; ++j) { o0[j] = (f16)acc[j]; o1[j] = (f16)acc[8 + j]; }
  f16* op = out + (((size_t)b * 64 + h) * 64 + w) * 64 + cg * 16;
  *(f16x8*)op = o0;
  *(f16x8*)(op + 8) = o1;
}

// partial[4][256][16] -> mean -> FC 256->10 -> 1. One block, wave per b.
__global__ void __launch_bounds__(256)
fc_kernel(const float* __restrict__ partial, const float* __restrict__ fw1,
          const float* __restrict__ fb1, const float* __restrict__ fw2,
          const float* __restrict__ fb2, float* __restrict__ outp) {
  const int t = threadIdx.x;
  const int b = t >> 6, lane = t & 63;
  float pooled[4];
  #pragma unroll
  for (int k = 0; k < 4; ++k) {
    int c = lane + 64 * k;
    float s = 0.f;
    #pragma unroll
    for (int p = 0; p < 16; ++p) s += partial[(size_t)(b * 256 + c) * 16 + p];
    pooled[k] = s * (1.f / 4096.f);
  }
  float o = 0.f;
  for (int i = 0; i < 10; ++i) {
    float d = 0.f;
    #pragma unroll
    for (int k = 0; k < 4; ++k) d += pooled[k] * fw1[i * 256 + lane + 64 * k];
    #pragma unroll
    for (int off = 32; off > 0; off >>= 1) d += __shfl_down(d, off, 64);
    o += (d + fb1[i]) * fw2[i];
  }
  if (lane == 0) outp[b] = o + fb2[0];
}

extern "C" void kernel_launch(void* const* d_in, const int* in_sizes, int n_in,
                              void* d_out, int out_size, void* d_ws, size_t ws_size,
                              hipStream_t stream) {
  const float* low_key    = (const float*)d_in[0];
  const float* low_nonkey = (const float*)d_in[1];
  const float* atten      = (const float*)d_in[2];
  const float* w1 = (const float*)d_in[3];  const float* bn1 = (const float*)d_in[4];
  const float* w2 = (const float*)d_in[5];  const float* bn2 = (const float*)d_in[6];
  const float* w3 = (const float*)d_in[7];  const float* bn3 = (const float*)d_in[8];
  const float* w4 = (const float*)d_in[9];  const float* bn4 = (const float*)d_in[10];
  const float* w5 = (const float*)d_in[11]; const float* bn5 = (const float*)d_in[12];
  const float* fw1 = (const float*)d_in[13]; const float* fb1 = (const float*)d_in[14];
  const float* fw2 = (const float*)d_in[15]; const float* fb2 = (const float*)d_in[16];

  // Pacc region (67 MB) temporally aliased with X2/X3/Pacc2:
  //   conv1 writes Pacc -> kr1 -> conv2 writes Pacc2 -> kr2 writes X2 ->
  //   weighting writes X3 -> conv3 reads X3 -> conv4 reclaims whole Pacc.
  f16* T    = (f16*)d_ws;              // 16,777,216
  f16* X1   = T + 16777216;            // 4,194,304
  f16* Y    = X1 + 4194304;            // 4,194,304
  f16* wt1  = Y + 4194304;             // 2,359,296
  f16* wt2  = wt1 + 2359296;           // 147,456
  f16* wt3  = wt2 + 147456;            // 147,456
  f16* wt4  = wt3 + 147456;            // 2,359,296
  f16* wt5  = wt4 + 2359296;           // 589,824
  float* P    = (float*)(wt5 + 589824);   // 16,384 f32
  float* Pacc = P + 16384;                // 16,777,216 f32 (4 slabs x 4,194,304)
  f16* X2     = (f16*)Pacc;               // 1,048,576 f16 (first 0.5M f32)
  f16* X3     = X2 + 1048576;             // next 0.5M f32
  float* Pacc2 = Pacc + 2097152;          // 4 slabs x 1,048,576 f32

  dim3 blk(256);
  wtrans_kernel<<<(256 * 1024 * 9 + 255) / 256, blk, 0, stream>>>(w1, wt1, 256, 1024);
  wtrans_kernel<<<(64 * 256 * 9 + 255) / 256, blk, 0, stream>>>(w2, wt2, 64, 256);
  wtrans_kernel<<<(256 * 64 * 9 + 255) / 256, blk, 0, stream>>>(w3, wt3, 256, 64);
  wtrans_kernel<<<(256 * 1024 * 9 + 255) / 256, blk, 0, stream>>>(w4, wt4, 256, 1024);
  wtrans_kernel<<<(256 * 256 * 9 + 255) / 256, blk, 0, stream>>>(w5, wt5, 256, 256);

  // lk -> NHWC f16
  nchw2nhwc<<<dim3(256, 16), blk, 0, stream>>>(low_key, T);
  // x1 = cbr(lk, w1): A-from-global conv, K-split 4 -> Pacc -> kreduce
  conv_bigK<<<dim3(128, 1, 4), blk, 0, stream>>>(T, wt1, Pacc);
  kreduce<<<1024, blk, 0, stream>>>(Pacc, bn1, X1, 256, 4);
  // x2 = cbr(x1, w2): K-split 4 -> Pacc2 -> kreduce
  conv_mfma<<<dim3(64, 1, 4), blk, 0, stream>>>(X1, nullptr, wt2, bn2, nullptr, Pacc2, nullptr, 256, 64, 4);
  kreduce<<<256, blk, 0, stream>>>(Pacc2, bn2, X2, 64, 4);
  // x3 = weighting(x2)
  weighting_nhwc<<<dim3(64, NB), blk, 0, stream>>>(X2, atten, X3);
  // x4 = cbr(x3, w3)  (writes X1)
  conv_mfma<<<dim3(64, 4, 1), blk, 0, stream>>>(X3, nullptr, wt3, bn3, X1, nullptr, nullptr, 64, 256, 1);
  // lnk -> NHWC f16 (T free after conv1)
  nchw2nhwc<<<dim3(256, 16), blk, 0, stream>>>(low_nonkey, T);
  // y = cbr(lnk, w4): X2/X3/Pacc2 dead -> Pacc reusable
  conv_bigK<<<dim3(128, 1, 4), blk, 0, stream>>>(T, wt4, Pacc);
  kreduce<<<1024, blk, 0, stream>>>(Pacc, bn4, Y, 256, 4);
  // z = cbr(x4 - y, w5) -> pooled partials (NO K-split: BN+ReLU nonlinear)
  conv_mfma<<<dim3(64, 4, 1), blk, 0, stream>>>(X1, Y, wt5, bn5, nullptr, nullptr, P, 256, 256, 1);
  // mean -> FC -> FC
  fc_kernel<<<1, 256, 0, stream>>>(P, fw1, fb1, fw2, fb2, (float*)d_out);
}

// Round 14
// 396.597 us; speedup vs baseline: 1.3054x; 1.0265x over previous
//
#include <hip/hip_runtime.h>
#include <math.h>

typedef _Float16 f16;
typedef f16 f16x4 __attribute__((ext_vector_type(4)));
typedef f16 f16x8 __attribute__((ext_vector_type(8)));
typedef float f32x4 __attribute__((ext_vector_type(4)));

#define NB 4

// Transpose + convert conv weights: w[co][ci][9] f32 -> wt[k][co][ci] f16.
__global__ void __launch_bounds__(256)
wtrans_kernel(const float* __restrict__ w, f16* __restrict__ wt, int Co, int Cin) {
  int idx = blockIdx.x * 256 + threadIdx.x;
  int total = Co * Cin * 9;
  if (idx >= total) return;
  int ci = idx % Cin, t2 = idx / Cin;
  int co = t2 % Co, k = t2 / Co;
  wt[idx] = (f16)w[((size_t)co * Cin + ci) * 9 + k];
}

// NCHW f32 -> NHWC f16 (Cin=1024 inputs). Block: one (b,h) x 64-channel chunk.
__global__ void __launch_bounds__(256)
nchw2nhwc(const float* __restrict__ in, f16* __restrict__ out) {
  __shared__ f16 s[64][66];
  const int t = threadIdx.x;
  const int bh = blockIdx.x, c0 = blockIdx.y * 64;
  const int b = bh >> 6, h = bh & 63;
  const int w = t & 63, cr = t >> 6;
  #pragma unroll
  for (int i = 0; i < 16; ++i) {
    int c = c0 + cr * 16 + i;
    s[cr * 16 + i][w] = (f16)in[(((size_t)b * 1024 + c) * 64 + h) * 64 + w];
  }
  __syncthreads();
  #pragma unroll
  for (int i = 0; i < 2; ++i) {
    int task = t + 256 * i;
    int oct = task & 7, w2 = task >> 3;
    f16x8 v;
    #pragma unroll
    for (int j = 0; j < 8; ++j) v[j] = s[oct * 8 + j][w2];
    *(f16x8*)(out + (((size_t)b * 64 + h) * 64 + w2) * 1024 + c0 + oct * 8) = v;
  }
}

// conv1/conv4 (Cin=1024, Co=256): A-from-global + B-from-LDS implicit GEMM.
// 256 thr = 4 waves, each wave = ONE 64-co group x 128 px (4m x 8n frags).
// Block = 256co x 2 rows -> input staged ONCE for all 256 co (xs 21 KB only).
// K-split 4: **blockIdx.x = z (K-piece)** so linear block id = z + 4*tile ->
// round-robin XCD assignment clusters ONE 1.18 MB weight slab per XCD
// (L2-resident; R13's (tile,z) order thrashed 4.7 MB across every XCD).
// A-frags stream from wt[tap][co][ci] with 2-buffer per-tap register prefetch.
// Raw f32 accs -> pacc (linear; kreduce applies BN+ReLU after the sum).
__global__ void __launch_bounds__(256, 2)
conv_bigK(const f16* __restrict__ in, const f16* __restrict__ wt,
          float* __restrict__ pacc) {
  constexpr int Cin = 1024, Co = 256, NC = 8;
  __shared__ __align__(16) f16 xs[4][66][40];

  const int t = threadIdx.x;
  const int zz = blockIdx.x;         // K-piece 0..3 (fastest-varying -> XCD-clustered)
  const int tile = blockIdx.y;       // 128 = 4b x 32 row-pairs
  const int b = tile >> 5;
  const int h0 = (tile & 31) * 2;
  const int ciBase = zz * 256;
  const int wid = t >> 6, lane = t & 63;
  const int l15 = lane & 15, lg = lane >> 4;
  const int koff = lg * 8;

  f32x4 acc[4][8];
  #pragma unroll
  for (int m = 0; m < 4; ++m)
    #pragma unroll
    for (int n = 0; n < 8; ++n)
      #pragma unroll
      for (int r = 0; r < 4; ++r) acc[m][n][r] = 0.f;

  const f16* inb = in + (size_t)b * Cin * 4096;
  const int wS = t >> 2, octS = t & 3;
  f16x8 ireg[4];

  auto load_stage = [&](int c) {
    int ci0 = ciBase + c * 32;
    #pragma unroll
    for (int r = 0; r < 4; ++r) {
      int gh = h0 - 1 + r;
      f16x8 v = {};
      if ((unsigned)gh < 64u)
        v = *(const f16x8*)(inb + ((size_t)gh * 64 + wS) * Cin + ci0 + octS * 8);
      ireg[r] = v;
    }
  };
  auto write_stage = [&]() {
    #pragma unroll
    for (int r = 0; r < 4; ++r)
      *(f16x8*)&xs[r][wS + 1][octS * 8] = ireg[r];
  };

  // A-fragment base for this thread (per m add m*16*Cin; per tap add tap*Co*Cin)
  const f16* wA = wt + (size_t)(wid * 64 + l15) * Cin + koff + ciBase;

  f16x8 afA[4], afB[4];
  #pragma unroll
  for (int m = 0; m < 4; ++m)        // prologue: A(c=0, tap=0)
    afA[m] = *(const f16x8*)(wA + (size_t)m * 16 * Cin);

  if (t < 32) {                      // zero w-halo columns once
    int r = t >> 3, side = (t >> 2) & 1, oc = t & 3;
    f16x8 z = {};
    *(f16x8*)&xs[r][side * 65][oc * 8] = z;
  }
  load_stage(0);
  write_stage();
  __syncthreads();

  for (int c = 0; c < NC; ++c) {
    if (c + 1 < NC) load_stage(c + 1);   // input globals fly during MFMA phase
    #pragma unroll
    for (int tap = 0; tap < 9; ++tap) {
      const int dh = tap / 3 - 1, dw = tap % 3 - 1;
      const int nt = (tap < 8) ? tap + 1 : 0;
      const int ncc = (tap < 8) ? c : c + 1;
      const bool doPf = (tap < 8) || (c + 1 < NC);
      if ((tap & 1) == 0) {
        if (doPf)
          #pragma unroll
          for (int m = 0; m < 4; ++m)
            afB[m] = *(const f16x8*)(wA + ((size_t)nt * Co + m * 16) * Cin + ncc * 32);
        #pragma unroll
        for (int n = 0; n < 8; ++n) {
          const f16x8 bf = *(const f16x8*)&xs[(n >> 2) + dh + 1][(n & 3) * 16 + l15 + 1 + dw][koff];
          #pragma unroll
          for (int m = 0; m < 4; ++m)
            acc[m][n] = __builtin_amdgcn_mfma_f32_16x16x32_f16(afA[m], bf, acc[m][n], 0, 0, 0);
        }
      } else {
        if (doPf)
          #pragma unroll
          for (int m = 0; m < 4; ++m)
            afA[m] = *(const f16x8*)(wA + ((size_t)nt * Co + m * 16) * Cin + ncc * 32);
        #pragma unroll
        for (int n = 0; n < 8; ++n) {
          const f16x8 bf = *(const f16x8*)&xs[(n >> 2) + dh + 1][(n & 3) * 16 + l15 + 1 + dw][koff];
          #pragma unroll
          for (int m = 0; m < 4; ++m)
            acc[m][n] = __builtin_amdgcn_mfma_f32_16x16x32_f16(afB[m], bf, acc[m][n], 0, 0, 0);
        }
      }
    }
    #pragma unroll
    for (int m = 0; m < 4; ++m) afA[m] = afB[m];  // tap8 prefetched (c+1, tap0)
    __syncthreads();                  // all xs reads of chunk c done
    if (c + 1 < NC) write_stage();
    __syncthreads();                  // chunk c+1 visible
  }

  // raw f32 accs -> pacc[z][b][px][co] (kreduce applies BN+ReLU after sum)
  float* pb = pacc + (size_t)zz * 4194304 + (size_t)b * 4096 * Co;
  #pragma unroll
  for (int m = 0; m < 4; ++m)
    #pragma unroll
    for (int n = 0; n < 8; ++n) {
      int px = (h0 + (n >> 2)) * 64 + (n & 3) * 16 + l15;
      *(f32x4*)(pb + (size_t)px * Co + wid * 64 + m * 16 + lg * 4) = acc[m][n];
    }
}

// Mid-size convs (conv2/3/5): both operands in LDS, wave 64co x 64px (4x4).
// kspl via blockIdx.z: pacc!=null -> raw accs (linear). out!=null -> BN+ReLU
// f16 NHWC. Neither -> pooled partials (conv5, kspl MUST be 1: nonlinear).
__global__ void __launch_bounds__(256, 1)
conv_mfma(const f16* __restrict__ in, const f16* __restrict__ in2,
          const f16* __restrict__ wt, const float* __restrict__ bn,
          f16* __restrict__ out, float* __restrict__ pacc,
          float* __restrict__ partial, int Cin, int Co, int kspl) {
  __shared__ __align__(16) f16 xs[6][66][40];
  __shared__ __align__(16) f16 ws[9][64][40];
  __shared__ float s_red[4][64];

  const int t = threadIdx.x;
  const int tile = blockIdx.x;       // 64 = 4b x 16 row-quads
  const int b = tile >> 4;
  const int h0 = (tile & 15) * 4;
  const int co_blk = blockIdx.y * 64;
  const int ciBase = blockIdx.z * (Cin / kspl);
  const int NC = (Cin / kspl) >> 5;
  const int wid = t >> 6, lane = t & 63;
  const int l15 = lane & 15, lg = lane >> 4;
  const int koff = lg * 8;

  f32x4 acc[4][4];
  #pragma unroll
  for (int m = 0; m < 4; ++m)
    #pragma unroll
    for (int n = 0; n < 4; ++n)
      #pragma unroll
      for (int r = 0; r < 4; ++r) acc[m][n][r] = 0.f;

  const f16* inb = in + (size_t)b * Cin * 4096;
  const f16* inb2 = in2 ? in2 + (size_t)b * Cin * 4096 : nullptr;

  const int wS = t >> 2, octS = t & 3;
  f16x8 ireg[6], wreg[9];

  auto load_stage = [&](int ci0) {
    #pragma unroll
    for (int r = 0; r < 6; ++r) {
      int gh = h0 - 1 + r;
      f16x8 v = {};
      if ((unsigned)gh < 64u) {
        size_t off = ((size_t)gh * 64 + wS) * Cin + ci0 + octS * 8;
        v = *(const f16x8*)(inb + off);
        if (inb2) { f16x8 v2 = *(const f16x8*)(inb2 + off); v = v - v2; }
      }
      ireg[r] = v;
    }
    #pragma unroll
    for (int i = 0; i < 9; ++i) {
      int s = t + 256 * i;
      int oct = s & 3, co = (s >> 2) & 63, k = s >> 8;
      wreg[i] = *(const f16x8*)(wt + ((size_t)k * Co + co_blk + co) * Cin + ci0 + oct * 8);
    }
  };
  auto write_stage = [&]() {
    #pragma unroll
    for (int r = 0; r < 6; ++r)
      *(f16x8*)&xs[r][wS + 1][octS * 8] = ireg[r];
    #pragma unroll
    for (int i = 0; i < 9; ++i) {
      int s = t + 256 * i;
      int oct = s & 3, co = (s >> 2) & 63, k = s >> 8;
      *(f16x8*)&ws[k][co][oct * 8] = wreg[i];
    }
  };

  if (t < 48) {
    int r = t >> 3, side = (t >> 2) & 1, oc = t & 3;
    f16x8 z = {};
    *(f16x8*)&xs[r][side * 65][oc * 8] = z;
  }
  load_stage(ciBase);
  write_stage();
  __syncthreads();

  for (int c = 0; c < NC; ++c) {
    if (c + 1 < NC) load_stage(ciBase + ((c + 1) << 5));
    #pragma unroll
    for (int tap = 0; tap < 9; ++tap) {
      const int dh = tap / 3 - 1, dw = tap % 3 - 1;
      f16x8 af[4];
      #pragma unroll
      for (int m = 0; m < 4; ++m)
        af[m] = *(const f16x8*)&ws[tap][m * 16 + l15][koff];
      #pragma unroll
      for (int n = 0; n < 4; ++n) {
        const f16x8 bf = *(const f16x8*)&xs[wid + dh + 1][n * 16 + l15 + 1 + dw][koff];
        #pragma unroll
        for (int m = 0; m < 4; ++m)
          acc[m][n] = __builtin_amdgcn_mfma_f32_16x16x32_f16(af[m], bf, acc[m][n], 0, 0, 0);
      }
    }
    __syncthreads();
    if (c + 1 < NC) write_stage();
    __syncthreads();
  }

  if (pacc) {
    float* pb = pacc + (size_t)blockIdx.z * 16384 * Co + (size_t)b * 4096 * Co;
    #pragma unroll
    for (int m = 0; m < 4; ++m)
      #pragma unroll
      for (int n = 0; n < 4; ++n) {
        int px = (h0 + wid) * 64 + n * 16 + l15;
        *(f32x4*)(pb + (size_t)px * Co + co_blk + m * 16 + lg * 4) = acc[m][n];
      }
  } else if (out) {
    #pragma unroll
    for (int m = 0; m < 4; ++m) {
      float sc[4], sh[4];
      #pragma unroll
      for (int reg = 0; reg < 4; ++reg) {
        int co = co_blk + m * 16 + lg * 4 + reg;
        sc[reg] = bn[co] / sqrtf(bn[3 * Co + co] + 1e-5f);
        sh[reg] = bn[Co + co] - bn[2 * Co + co] * sc[reg];
      }
      #pragma unroll
      for (int n = 0; n < 4; ++n) {
        f16x4 v;
        #pragma unroll
        for (int reg = 0; reg < 4; ++reg)
          v[reg] = (f16)fmaxf(fmaf(acc[m][n][reg], sc[reg], sh[reg]), 0.f);
        *(f16x4*)(out + ((size_t)(b * 64 + h0 + wid) * 64 + n * 16 + l15) * Co
                      + co_blk + m * 16 + lg * 4) = v;
      }
    }
  } else {
    #pragma unroll
    for (int m = 0; m < 4; ++m)
      #pragma unroll
      for (int reg = 0; reg < 4; ++reg) {
        int co = co_blk + m * 16 + lg * 4 + reg;
        float sc = bn[co] / sqrtf(bn[3 * Co + co] + 1e-5f);
        float sh = bn[Co + co] - bn[2 * Co + co] * sc;
        float s = 0.f;
        #pragma unroll
        for (int n = 0; n < 4; ++n)
          s += fmaxf(fmaf(acc[m][n][reg], sc, sh), 0.f);
        s += __shfl_xor(s, 1, 64);
        s += __shfl_xor(s, 2, 64);
        s += __shfl_xor(s, 4, 64);
        s += __shfl_xor(s, 8, 64);
        if (l15 == 0) s_red[wid][m * 16 + lg * 4 + reg] = s;
      }
    __syncthreads();
    if (t < 64) {
      float v = s_red[0][t] + s_red[1][t] + s_red[2][t] + s_red[3][t];
      partial[((size_t)b * Co + co_blk + t) * 16 + (tile & 15)] = v;
    }
  }
}

// Sum nslab K-slices + BN + ReLU -> NHWC f16. Grid: 4*Co blocks.
__global__ void __launch_bounds__(256)
kreduce(const float* __restrict__ pacc, const float* __restrict__ bn,
        f16* __restrict__ out, int Co, int nslab) {
  const int t = threadIdx.x;
  const size_t slab = (size_t)16384 * Co;
  const int cq = t % (Co >> 2);
  float sc[4], sh[4];
  #pragma unroll
  for (int r = 0; r < 4; ++r) {
    int co = cq * 4 + r;
    sc[r] = bn[co] / sqrtf(bn[3 * Co + co] + 1e-5f);
    sh[r] = bn[Co + co] - bn[2 * Co + co] * sc[r];
  }
  #pragma unroll
  for (int i = 0; i < 4; ++i) {
    size_t idx = (size_t)blockIdx.x * 1024 + i * 256 + t;
    f32x4 a = *(const f32x4*)(pacc + idx * 4);
    for (int s = 1; s < nslab; ++s) {
      f32x4 b2 = *(const f32x4*)(pacc + slab * s + idx * 4);
      #pragma unroll
      for (int r = 0; r < 4; ++r) a[r] += b2[r];
    }
    f16x4 v;
    #pragma unroll
    for (int r = 0; r < 4; ++r)
      v[r] = (f16)fmaxf(fmaf(a[r], sc[r], sh[r]), 0.f);
    *(f16x4*)(out + idx * 4) = v;
  }
}

// out[b,h,w,c] = sum_k atten[b,h,w,k] * x[b,h+dh,w+dw,c], NHWC f16, C=64.
__global__ void __launch_bounds__(256)
weighting_nhwc(const f16* __restrict__ x, const float* __restrict__ atten,
               f16* __restrict__ out) {
  __shared__ float s_a[64 * 81];
  const int h = blockIdx.x, b = blockIdx.y;
  const int t = threadIdx.x;
  for (int idx = t; idx < 64 * 81; idx += 256)
    s_a[idx] = atten[(size_t)((b * 64 + h) * 64) * 81 + idx];
  __syncthreads();

  const int w = t & 63, cg = t >> 6;
  float acc[16];
  #pragma unroll
  for (int j = 0; j < 16; ++j) acc[j] = 0.f;

  for (int dh = -4; dh <= 4; ++dh) {
    int hh = h + dh;
    if ((unsigned)hh >= 64u) continue;
    #pragma unroll
    for (int dw = -4; dw <= 4; ++dw) {
      int ww = w + dw;
      if ((unsigned)ww >= 64u) continue;
      float a = s_a[w * 81 + (dh + 4) * 9 + (dw + 4)];
      const f16* xp = x + (((size_t)b * 64 + hh) * 64 + ww) * 64 + cg * 16;
      f16x8 v0 = *(const f16x8*)xp;
      f16x8 v1 = *(const f16x8*)(xp + 8);
      #pragma unroll
      for (int j = 0; j < 8; ++j) {
        acc[j]     = fmaf(a, (float)v0[j], acc[j]);
        acc[8 + j] = fmaf(a, (float)v1[j], acc[8 + j]);
      }
    }
  }
  f16x8 o0, o1;
  #pragma unroll
  for (int j = 0; j < 8; ++j) { o0[j] = (f16)acc[j]; o1[j] = (f16)acc[8 + j]; }
  f16* op = out + (((size_t)b * 64 + h) * 64 + w) * 64 + cg * 16;
  *(f16x8*)op = o0;
  *(f16x8*)(op + 8) = o1;
}

// partial[4][256][16] -> mean -> FC 256->10 -> 1. One block, wave per b.
__global__ void __launch_bounds__(256)
fc_kernel(const float* __restrict__ partial, const float* __restrict__ fw1,
          const float* __restrict__ fb1, const float* __restrict__ fw2,
          const float* __restrict__ fb2, float* __restrict__ outp) {
  const int t = threadIdx.x;
  const int b = t >> 6, lane = t & 63;
  float pooled[4];
  #pragma unroll
  for (int k = 0; k < 4; ++k) {
    int c = lane + 64 * k;
    float s = 0.f;
    #pragma unroll
    for (int p = 0; p < 16; ++p) s += partial[(size_t)(b * 256 + c) * 16 + p];
    pooled[k] = s * (1.f / 4096.f);
  }
  float o = 0.f;
  for (int i = 0; i < 10; ++i) {
    float d = 0.f;
    #pragma unroll
    for (int k = 0; k < 4; ++k) d += pooled[k] * fw1[i * 256 + lane + 64 * k];
    #pragma unroll
    for (int off = 32; off > 0; off >>= 1) d += __shfl_down(d, off, 64);
    o += (d + fb1[i]) * fw2[i];
  }
  if (lane == 0) outp[b] = o + fb2[0];
}

extern "C" void kernel_launch(void* const* d_in, const int* in_sizes, int n_in,
                              void* d_out, int out_size, void* d_ws, size_t ws_size,
                              hipStream_t stream) {
  const float* low_key    = (const float*)d_in[0];
  const float* low_nonkey = (const float*)d_in[1];
  const float* atten      = (const float*)d_in[2];
  const float* w1 = (const float*)d_in[3];  const float* bn1 = (const float*)d_in[4];
  const float* w2 = (const float*)d_in[5];  const float* bn2 = (const float*)d_in[6];
  const float* w3 = (const float*)d_in[7];  const float* bn3 = (const float*)d_in[8];
  const float* w4 = (const float*)d_in[9];  const float* bn4 = (const float*)d_in[10];
  const float* w5 = (const float*)d_in[11]; const float* bn5 = (const float*)d_in[12];
  const float* fw1 = (const float*)d_in[13]; const float* fb1 = (const float*)d_in[14];
  const float* fw2 = (const float*)d_in[15]; const float* fb2 = (const float*)d_in[16];

  // Pacc region (67 MB) temporally aliased with X2/X3/Pacc2:
  //   conv1 writes Pacc -> kr1 -> conv2 writes Pacc2 -> kr2 writes X2 ->
  //   weighting writes X3 -> conv3 reads X3 -> conv4 reclaims whole Pacc.
  f16* T    = (f16*)d_ws;              // 16,777,216
  f16* X1   = T + 16777216;            // 4,194,304
  f16* Y    = X1 + 4194304;            // 4,194,304
  f16* wt1  = Y + 4194304;             // 2,359,296
  f16* wt2  = wt1 + 2359296;           // 147,456
  f16* wt3  = wt2 + 147456;            // 147,456
  f16* wt4  = wt3 + 147456;            // 2,359,296
  f16* wt5  = wt4 + 2359296;           // 589,824
  float* P    = (float*)(wt5 + 589824);   // 16,384 f32
  float* Pacc = P + 16384;                // 16,777,216 f32 (4 slabs x 4,194,304)
  f16* X2     = (f16*)Pacc;               // 1,048,576 f16 (first 0.5M f32)
  f16* X3     = X2 + 1048576;             // next 0.5M f32
  float* Pacc2 = Pacc + 2097152;          // 4 slabs x 1,048,576 f32

  dim3 blk(256);
  wtrans_kernel<<<(256 * 1024 * 9 + 255) / 256, blk, 0, stream>>>(w1, wt1, 256, 1024);
  wtrans_kernel<<<(64 * 256 * 9 + 255) / 256, blk, 0, stream>>>(w2, wt2, 64, 256);
  wtrans_kernel<<<(256 * 64 * 9 + 255) / 256, blk, 0, stream>>>(w3, wt3, 256, 64);
  wtrans_kernel<<<(256 * 1024 * 9 + 255) / 256, blk, 0, stream>>>(w4, wt4, 256, 1024);
  wtrans_kernel<<<(256 * 256 * 9 + 255) / 256, blk, 0, stream>>>(w5, wt5, 256, 256);

  // lk -> NHWC f16
  nchw2nhwc<<<dim3(256, 16), blk, 0, stream>>>(low_key, T);
  // x1 = cbr(lk, w1): z-clustered A-from-global conv -> Pacc -> kreduce
  conv_bigK<<<dim3(4, 128, 1), blk, 0, stream>>>(T, wt1, Pacc);
  kreduce<<<1024, blk, 0, stream>>>(Pacc, bn1, X1, 256, 4);
  // x2 = cbr(x1, w2): K-split 4 -> Pacc2 -> kreduce
  conv_mfma<<<dim3(64, 1, 4), blk, 0, stream>>>(X1, nullptr, wt2, bn2, nullptr, Pacc2, nullptr, 256, 64, 4);
  kreduce<<<256, blk, 0, stream>>>(Pacc2, bn2, X2, 64, 4);
  // x3 = weighting(x2)
  weighting_nhwc<<<dim3(64, NB), blk, 0, stream>>>(X2, atten, X3);
  // x4 = cbr(x3, w3)  (writes X1)
  conv_mfma<<<dim3(64, 4, 1), blk, 0, stream>>>(X3, nullptr, wt3, bn3, X1, nullptr, nullptr, 64, 256, 1);
  // lnk -> NHWC f16 (T free after conv1)
  nchw2nhwc<<<dim3(256, 16), blk, 0, stream>>>(low_nonkey, T);
  // y = cbr(lnk, w4): X2/X3/Pacc2 dead -> Pacc reusable
  conv_bigK<<<dim3(4, 128, 1), blk, 0, stream>>>(T, wt4, Pacc);
  kreduce<<<1024, blk, 0, stream>>>(Pacc, bn4, Y, 256, 4);
  // z = cbr(x4 - y, w5) -> pooled partials (NO K-split: BN+ReLU nonlinear)
  conv_mfma<<<dim3(64, 4, 1), blk, 0, stream>>>(X1, Y, wt5, bn5, nullptr, nullptr, P, 256, 256, 1);
  // mean -> FC -> FC
  fc_kernel<<<1, 256, 0, stream>>>(P, fw1, fb1, fw2, fb2, (float*)d_out);
}

// Round 15
// 396.103 us; speedup vs baseline: 1.3071x; 1.0012x over previous
//
#include <hip/hip_runtime.h>
#include <math.h>

typedef _Float16 f16;
typedef f16 f16x4 __attribute__((ext_vector_type(4)));
typedef f16 f16x8 __attribute__((ext_vector_type(8)));
typedef float f32x4 __attribute__((ext_vector_type(4)));

#define NB 4

// Transpose + convert conv weights: w[co][ci][9] f32 -> wt[k][co][ci] f16.
__global__ void __launch_bounds__(256)
wtrans_kernel(const float* __restrict__ w, f16* __restrict__ wt, int Co, int Cin) {
  int idx = blockIdx.x * 256 + threadIdx.x;
  int total = Co * Cin * 9;
  if (idx >= total) return;
  int ci = idx % Cin, t2 = idx / Cin;
  int co = t2 % Co, k = t2 / Co;
  wt[idx] = (f16)w[((size_t)co * Cin + ci) * 9 + k];
}

// NCHW f32 -> NHWC f16 (Cin=1024 inputs). Block: one (b,h) x 64-channel chunk.
__global__ void __launch_bounds__(256)
nchw2nhwc(const float* __restrict__ in, f16* __restrict__ out) {
  __shared__ f16 s[64][66];
  const int t = threadIdx.x;
  const int bh = blockIdx.x, c0 = blockIdx.y * 64;
  const int b = bh >> 6, h = bh & 63;
  const int w = t & 63, cr = t >> 6;
  #pragma unroll
  for (int i = 0; i < 16; ++i) {
    int c = c0 + cr * 16 + i;
    s[cr * 16 + i][w] = (f16)in[(((size_t)b * 1024 + c) * 64 + h) * 64 + w];
  }
  __syncthreads();
  #pragma unroll
  for (int i = 0; i < 2; ++i) {
    int task = t + 256 * i;
    int oct = task & 7, w2 = task >> 3;
    f16x8 v;
    #pragma unroll
    for (int j = 0; j < 8; ++j) v[j] = s[oct * 8 + j][w2];
    *(f16x8*)(out + (((size_t)b * 64 + h) * 64 + w2) * 1024 + c0 + oct * 8) = v;
  }
}

// conv1/conv4 (Cin=1024, Co=256): A-from-global + B-from-LDS implicit GEMM.
// 256 thr = 4 waves; wave = 64co x 128px (4m x 8n frags); block = 256co x 2 rows.
// blockIdx.x = z (K-piece) -> one 1.18 MB weight slab per XCD (L2-resident).
// A-pipeline: THREE-buffer rotation, prefetch 2 taps ahead (64 MFMA ~ 310-620
// cyc cover >= L2 ~200 cyc latency; R14's 1-tap-ahead = 155 cyc was the stall).
// Slot indices (tap%3, (tap+2)%3) are compile-time in the unrolled loop.
// Raw f32 accs -> pacc (linear; kreduce applies BN+ReLU after the sum).
__global__ void __launch_bounds__(256, 2)
conv_bigK(const f16* __restrict__ in, const f16* __restrict__ wt,
          float* __restrict__ pacc) {
  constexpr int Cin = 1024, Co = 256, NC = 8;
  __shared__ __align__(16) f16 xs[4][66][40];

  const int t = threadIdx.x;
  const int zz = blockIdx.x;         // K-piece 0..3 (fastest-varying -> XCD-clustered)
  const int tile = blockIdx.y;       // 128 = 4b x 32 row-pairs
  const int b = tile >> 5;
  const int h0 = (tile & 31) * 2;
  const int ciBase = zz * 256;
  const int wid = t >> 6, lane = t & 63;
  const int l15 = lane & 15, lg = lane >> 4;
  const int koff = lg * 8;

  f32x4 acc[4][8];
  #pragma unroll
  for (int m = 0; m < 4; ++m)
    #pragma unroll
    for (int n = 0; n < 8; ++n)
      #pragma unroll
      for (int r = 0; r < 4; ++r) acc[m][n][r] = 0.f;

  const f16* inb = in + (size_t)b * Cin * 4096;
  const int wS = t >> 2, octS = t & 3;
  f16x8 ireg[4];

  auto load_stage = [&](int c) {
    int ci0 = ciBase + c * 32;
    #pragma unroll
    for (int r = 0; r < 4; ++r) {
      int gh = h0 - 1 + r;
      f16x8 v = {};
      if ((unsigned)gh < 64u)
        v = *(const f16x8*)(inb + ((size_t)gh * 64 + wS) * Cin + ci0 + octS * 8);
      ireg[r] = v;
    }
  };
  auto write_stage = [&]() {
    #pragma unroll
    for (int r = 0; r < 4; ++r)
      *(f16x8*)&xs[r][wS + 1][octS * 8] = ireg[r];
  };

  // A-fragment base for this thread (per m add m*16*Cin; per tap add tap*Co*Cin)
  const f16* wA = wt + (size_t)(wid * 64 + l15) * Cin + koff + ciBase;

  f16x8 af[3][4];                    // 3-slot rotation, 2-taps-ahead prefetch
  #pragma unroll
  for (int m = 0; m < 4; ++m) {      // prologue: slots 0,1 = (c=0, taps 0,1)
    af[0][m] = *(const f16x8*)(wA + (size_t)m * 16 * Cin);
    af[1][m] = *(const f16x8*)(wA + ((size_t)1 * Co + m * 16) * Cin);
  }

  if (t < 32) {                      // zero w-halo columns once
    int r = t >> 3, side = (t >> 2) & 1, oc = t & 3;
    f16x8 z = {};
    *(f16x8*)&xs[r][side * 65][oc * 8] = z;
  }
  load_stage(0);
  write_stage();
  __syncthreads();

  for (int c = 0; c < NC; ++c) {
    if (c + 1 < NC) load_stage(c + 1);   // input globals fly during MFMA phase
    #pragma unroll
    for (int tap = 0; tap < 9; ++tap) {
      const int dh = tap / 3 - 1, dw = tap % 3 - 1;
      // prefetch tap+2 (wraps into chunk c+1 taps 0/1; A is xs-independent)
      const int pf_tap = (tap < 7) ? tap + 2 : tap - 7;
      const int pf_c = (tap < 7) ? c : c + 1;
      const bool doPf = (tap < 7) || (c + 1 < NC);
      if (doPf)
        #pragma unroll
        for (int m = 0; m < 4; ++m)
          af[(tap + 2) % 3][m] =
              *(const f16x8*)(wA + ((size_t)pf_tap * Co + m * 16) * Cin + pf_c * 32);
      #pragma unroll
      for (int n = 0; n < 8; ++n) {
        const f16x8 bf = *(const f16x8*)&xs[(n >> 2) + dh + 1][(n & 3) * 16 + l15 + 1 + dw][koff];
        #pragma unroll
        for (int m = 0; m < 4; ++m)
          acc[m][n] = __builtin_amdgcn_mfma_f32_16x16x32_f16(af[tap % 3][m], bf, acc[m][n], 0, 0, 0);
      }
    }
    __syncthreads();                  // all xs reads of chunk c done
    if (c + 1 < NC) write_stage();
    __syncthreads();                  // chunk c+1 visible
  }

  // raw f32 accs -> pacc[z][b][px][co] (kreduce applies BN+ReLU after sum)
  float* pb = pacc + (size_t)zz * 4194304 + (size_t)b * 4096 * Co;
  #pragma unroll
  for (int m = 0; m < 4; ++m)
    #pragma unroll
    for (int n = 0; n < 8; ++n) {
      int px = (h0 + (n >> 2)) * 64 + (n & 3) * 16 + l15;
      *(f32x4*)(pb + (size_t)px * Co + wid * 64 + m * 16 + lg * 4) = acc[m][n];
    }
}

// Mid-size convs (conv2/3/5): both operands in LDS, wave 64co x 64px (4x4).
// kspl via blockIdx.z: pacc!=null -> raw accs (linear). out!=null -> BN+ReLU
// f16 NHWC. Neither -> pooled partials (conv5, kspl MUST be 1: nonlinear).
__global__ void __launch_bounds__(256, 1)
conv_mfma(const f16* __restrict__ in, const f16* __restrict__ in2,
          const f16* __restrict__ wt, const float* __restrict__ bn,
          f16* __restrict__ out, float* __restrict__ pacc,
          float* __restrict__ partial, int Cin, int Co, int kspl) {
  __shared__ __align__(16) f16 xs[6][66][40];
  __shared__ __align__(16) f16 ws[9][64][40];
  __shared__ float s_red[4][64];

  const int t = threadIdx.x;
  const int tile = blockIdx.x;       // 64 = 4b x 16 row-quads
  const int b = tile >> 4;
  const int h0 = (tile & 15) * 4;
  const int co_blk = blockIdx.y * 64;
  const int ciBase = blockIdx.z * (Cin / kspl);
  const int NC = (Cin / kspl) >> 5;
  const int wid = t >> 6, lane = t & 63;
  const int l15 = lane & 15, lg = lane >> 4;
  const int koff = lg * 8;

  f32x4 acc[4][4];
  #pragma unroll
  for (int m = 0; m < 4; ++m)
    #pragma unroll
    for (int n = 0; n < 4; ++n)
      #pragma unroll
      for (int r = 0; r < 4; ++r) acc[m][n][r] = 0.f;

  const f16* inb = in + (size_t)b * Cin * 4096;
  const f16* inb2 = in2 ? in2 + (size_t)b * Cin * 4096 : nullptr;

  const int wS = t >> 2, octS = t & 3;
  f16x8 ireg[6], wreg[9];

  auto load_stage = [&](int ci0) {
    #pragma unroll
    for (int r = 0; r < 6; ++r) {
      int gh = h0 - 1 + r;
      f16x8 v = {};
      if ((unsigned)gh < 64u) {
        size_t off = ((size_t)gh * 64 + wS) * Cin + ci0 + octS * 8;
        v = *(const f16x8*)(inb + off);
        if (inb2) { f16x8 v2 = *(const f16x8*)(inb2 + off); v = v - v2; }
      }
      ireg[r] = v;
    }
    #pragma unroll
    for (int i = 0; i < 9; ++i) {
      int s = t + 256 * i;
      int oct = s & 3, co = (s >> 2) & 63, k = s >> 8;
      wreg[i] = *(const f16x8*)(wt + ((size_t)k * Co + co_blk + co) * Cin + ci0 + oct * 8);
    }
  };
  auto write_stage = [&]() {
    #pragma unroll
    for (int r = 0; r < 6; ++r)
      *(f16x8*)&xs[r][wS + 1][octS * 8] = ireg[r];
    #pragma unroll
    for (int i = 0; i < 9; ++i) {
      int s = t + 256 * i;
      int oct = s & 3, co = (s >> 2) & 63, k = s >> 8;
      *(f16x8*)&ws[k][co][oct * 8] = wreg[i];
    }
  };

  if (t < 48) {
    int r = t >> 3, side = (t >> 2) & 1, oc = t & 3;
    f16x8 z = {};
    *(f16x8*)&xs[r][side * 65][oc * 8] = z;
  }
  load_stage(ciBase);
  write_stage();
  __syncthreads();

  for (int c = 0; c < NC; ++c) {
    if (c + 1 < NC) load_stage(ciBase + ((c + 1) << 5));
    #pragma unroll
    for (int tap = 0; tap < 9; ++tap) {
      const int dh = tap / 3 - 1, dw = tap % 3 - 1;
      f16x8 af[4];
      #pragma unroll
      for (int m = 0; m < 4; ++m)
        af[m] = *(const f16x8*)&ws[tap][m * 16 + l15][koff];
      #pragma unroll
      for (int n = 0; n < 4; ++n) {
        const f16x8 bf = *(const f16x8*)&xs[wid + dh + 1][n * 16 + l15 + 1 + dw][koff];
        #pragma unroll
        for (int m = 0; m < 4; ++m)
          acc[m][n] = __builtin_amdgcn_mfma_f32_16x16x32_f16(af[m], bf, acc[m][n], 0, 0, 0);
      }
    }
    __syncthreads();
    if (c + 1 < NC) write_stage();
    __syncthreads();
  }

  if (pacc) {
    float* pb = pacc + (size_t)blockIdx.z * 16384 * Co + (size_t)b * 4096 * Co;
    #pragma unroll
    for (int m = 0; m < 4; ++m)
      #pragma unroll
      for (int n = 0; n < 4; ++n) {
        int px = (h0 + wid) * 64 + n * 16 + l15;
        *(f32x4*)(pb + (size_t)px * Co + co_blk + m * 16 + lg * 4) = acc[m][n];
      }
  } else if (out) {
    #pragma unroll
    for (int m = 0; m < 4; ++m) {
      float sc[4], sh[4];
      #pragma unroll
      for (int reg = 0; reg < 4; ++reg) {
        int co = co_blk + m * 16 + lg * 4 + reg;
        sc[reg] = bn[co] / sqrtf(bn[3 * Co + co] + 1e-5f);
        sh[reg] = bn[Co + co] - bn[2 * Co + co] * sc[reg];
      }
      #pragma unroll
      for (int n = 0; n < 4; ++n) {
        f16x4 v;
        #pragma unroll
        for (int reg = 0; reg < 4; ++reg)
          v[reg] = (f16)fmaxf(fmaf(acc[m][n][reg], sc[reg], sh[reg]), 0.f);
        *(f16x4*)(out + ((size_t)(b * 64 + h0 + wid) * 64 + n * 16 + l15) * Co
                      + co_blk + m * 16 + lg * 4) = v;
      }
    }
  } else {
    #pragma unroll
    for (int m = 0; m < 4; ++m)
      #pragma unroll
      for (int reg = 0; reg < 4; ++reg) {
        int co = co_blk + m * 16 + lg * 4 + reg;
        float sc = bn[co] / sqrtf(bn[3 * Co + co] + 1e-5f);
        float sh = bn[Co + co] - bn[2 * Co + co] * sc;
        float s = 0.f;
        #pragma unroll
        for (int n = 0; n < 4; ++n)
          s += fmaxf(fmaf(acc[m][n][reg], sc, sh), 0.f);
        s += __shfl_xor(s, 1, 64);
        s += __shfl_xor(s, 2, 64);
        s += __shfl_xor(s, 4, 64);
        s += __shfl_xor(s, 8, 64);
        if (l15 == 0) s_red[wid][m * 16 + lg * 4 + reg] = s;
      }
    __syncthreads();
    if (t < 64) {
      float v = s_red[0][t] + s_red[1][t] + s_red[2][t] + s_red[3][t];
      partial[((size_t)b * Co + co_blk + t) * 16 + (tile & 15)] = v;
    }
  }
}

// Sum nslab K-slices + BN + ReLU -> NHWC f16. Grid: 4*Co blocks.
__global__ void __launch_bounds__(256)
kreduce(const float* __restrict__ pacc, const float* __restrict__ bn,
        f16* __restrict__ out, int Co, int nslab) {
  const int t = threadIdx.x;
  const size_t slab = (size_t)16384 * Co;
  const int cq = t % (Co >> 2);
  float sc[4], sh[4];
  #pragma unroll
  for (int r = 0; r < 4; ++r) {
    int co = cq * 4 + r;
    sc[r] = bn[co] / sqrtf(bn[3 * Co + co] + 1e-5f);
    sh[r] = bn[Co + co] - bn[2 * Co + co] * sc[r];
  }
  #pragma unroll
  for (int i = 0; i < 4; ++i) {
    size_t idx = (size_t)blockIdx.x * 1024 + i * 256 + t;
    f32x4 a = *(const f32x4*)(pacc + idx * 4);
    for (int s = 1; s < nslab; ++s) {
      f32x4 b2 = *(const f32x4*)(pacc + slab * s + idx * 4);
      #pragma unroll
      for (int r = 0; r < 4; ++r) a[r] += b2[r];
    }
    f16x4 v;
    #pragma unroll
    for (int r = 0; r < 4; ++r)
      v[r] = (f16)fmaxf(fmaf(a[r], sc[r], sh[r]), 0.f);
    *(f16x4*)(out + idx * 4) = v;
  }
}

// out[b,h,w,c] = sum_k atten[b,h,w,k] * x[b,h+dh,w+dw,c], NHWC f16, C=64.
__global__ void __launch_bounds__(256)
weighting_nhwc(const f16* __restrict__ x, const float* __restrict__ atten,
               f16* __restrict__ out) {
  __shared__ float s_a[64 * 81];
  const int h = blockIdx.x, b = blockIdx.y;
  const int t = threadIdx.x;
  for (int idx = t; idx < 64 * 81; idx += 256)
    s_a[idx] = atten[(size_t)((b * 64 + h) * 64) * 81 + idx];
  __syncthreads();

  const int w = t & 63, cg = t >> 6;
  float acc[16];
  #pragma unroll
  for (int j = 0; j < 16; ++j) acc[j] = 0.f;

  for (int dh = -4; dh <= 4; ++dh) {
    int hh = h + dh;
    if ((unsigned)hh >= 64u) continue;
    #pragma unroll
    for (int dw = -4; dw <= 4; ++dw) {
      int ww = w + dw;
      if ((unsigned)ww >= 64u) continue;
      float a = s_a[w * 81 + (dh + 4) * 9 + (dw + 4)];
      const f16* xp = x + (((size_t)b * 64 + hh) * 64 + ww) * 64 + cg * 16;
      f16x8 v0 = *(const f16x8*)xp;
      f16x8 v1 = *(const f16x8*)(xp + 8);
      #pragma unroll
      for (int j = 0; j < 8; ++j) {
        acc[j]     = fmaf(a, (float)v0[j], acc[j]);
        acc[8 + j] = fmaf(a, (float)v1[j], acc[8 + j]);
      }
    }
  }
  f16x8 o0, o1;
  #pragma unroll
  for (int j = 0; j < 8; ++j) { o0[j] = (f16)acc[j]; o1[j] = (f16)acc[8 + j]; }
  f16* op = out + (((size_t)b * 64 + h) * 64 + w) * 64 + cg * 16;
  *(f16x8*)op = o0;
  *(f16x8*)(op + 8) = o1;
}

// partial[4][256][16] -> mean -> FC 256->10 -> 1. One block, wave per b.
__global__ void __launch_bounds__(256)
fc_kernel(const float* __restrict__ partial, const float* __restrict__ fw1,
          const float* __restrict__ fb1, const float* __restrict__ fw2,
          const float* __restrict__ fb2, float* __restrict__ outp) {
  const int t = threadIdx.x;
  const int b = t >> 6, lane = t & 63;
  float pooled[4];
  #pragma unroll
  for (int k = 0; k < 4; ++k) {
    int c = lane + 64 * k;
    float s = 0.f;
    #pragma unroll
    for (int p = 0; p < 16; ++p) s += partial[(size_t)(b * 256 + c) * 16 + p];
    pooled[k] = s * (1.f / 4096.f);
  }
  float o = 0.f;
  for (int i = 0; i < 10; ++i) {
    float d = 0.f;
    #pragma unroll
    for (int k = 0; k < 4; ++k) d += pooled[k] * fw1[i * 256 + lane + 64 * k];
    #pragma unroll
    for (int off = 32; off > 0; off >>= 1) d += __shfl_down(d, off, 64);
    o += (d + fb1[i]) * fw2[i];
  }
  if (lane == 0) outp[b] = o + fb2[0];
}

extern "C" void kernel_launch(void* const* d_in, const int* in_sizes, int n_in,
                              void* d_out, int out_size, void* d_ws, size_t ws_size,
                              hipStream_t stream) {
  const float* low_key    = (const float*)d_in[0];
  const float* low_nonkey = (const float*)d_in[1];
  const float* atten      = (const float*)d_in[2];
  const float* w1 = (const float*)d_in[3];  const float* bn1 = (const float*)d_in[4];
  const float* w2 = (const float*)d_in[5];  const float* bn2 = (const float*)d_in[6];
  const float* w3 = (const float*)d_in[7];  const float* bn3 = (const float*)d_in[8];
  const float* w4 = (const float*)d_in[9];  const float* bn4 = (const float*)d_in[10];
  const float* w5 = (const float*)d_in[11]; const float* bn5 = (const float*)d_in[12];
  const float* fw1 = (const float*)d_in[13]; const float* fb1 = (const float*)d_in[14];
  const float* fw2 = (const float*)d_in[15]; const float* fb2 = (const float*)d_in[16];

  // Pacc region (67 MB) temporally aliased with X2/X3/Pacc2:
  //   conv1 writes Pacc -> kr1 -> conv2 writes Pacc2 -> kr2 writes X2 ->
  //   weighting writes X3 -> conv3 reads X3 -> conv4 reclaims whole Pacc.
  f16* T    = (f16*)d_ws;              // 16,777,216
  f16* X1   = T + 16777216;            // 4,194,304
  f16* Y    = X1 + 4194304;            // 4,194,304
  f16* wt1  = Y + 4194304;             // 2,359,296
  f16* wt2  = wt1 + 2359296;           // 147,456
  f16* wt3  = wt2 + 147456;            // 147,456
  f16* wt4  = wt3 + 147456;            // 2,359,296
  f16* wt5  = wt4 + 2359296;           // 589,824
  float* P    = (float*)(wt5 + 589824);   // 16,384 f32
  float* Pacc = P + 16384;                // 16,777,216 f32 (4 slabs x 4,194,304)
  f16* X2     = (f16*)Pacc;               // 1,048,576 f16 (first 0.5M f32)
  f16* X3     = X2 + 1048576;             // next 0.5M f32
  float* Pacc2 = Pacc + 2097152;          // 4 slabs x 1,048,576 f32

  dim3 blk(256);
  wtrans_kernel<<<(256 * 1024 * 9 + 255) / 256, blk, 0, stream>>>(w1, wt1, 256, 1024);
  wtrans_kernel<<<(64 * 256 * 9 + 255) / 256, blk, 0, stream>>>(w2, wt2, 64, 256);
  wtrans_kernel<<<(256 * 64 * 9 + 255) / 256, blk, 0, stream>>>(w3, wt3, 256, 64);
  wtrans_kernel<<<(256 * 1024 * 9 + 255) / 256, blk, 0, stream>>>(w4, wt4, 256, 1024);
  wtrans_kernel<<<(256 * 256 * 9 + 255) / 256, blk, 0, stream>>>(w5, wt5, 256, 256);

  // lk -> NHWC f16
  nchw2nhwc<<<dim3(256, 16), blk, 0, stream>>>(low_key, T);
  // x1 = cbr(lk, w1): z-clustered, 3-deep-A-prefetch conv -> Pacc -> kreduce
  conv_bigK<<<dim3(4, 128, 1), blk, 0, stream>>>(T, wt1, Pacc);
  kreduce<<<1024, blk, 0, stream>>>(Pacc, bn1, X1, 256, 4);
  // x2 = cbr(x1, w2): K-split 4 -> Pacc2 -> kreduce
  conv_mfma<<<dim3(64, 1, 4), blk, 0, stream>>>(X1, nullptr, wt2, bn2, nullptr, Pacc2, nullptr, 256, 64, 4);
  kreduce<<<256, blk, 0, stream>>>(Pacc2, bn2, X2, 64, 4);
  // x3 = weighting(x2)
  weighting_nhwc<<<dim3(64, NB), blk, 0, stream>>>(X2, atten, X3);
  // x4 = cbr(x3, w3)  (writes X1)
  conv_mfma<<<dim3(64, 4, 1), blk, 0, stream>>>(X3, nullptr, wt3, bn3, X1, nullptr, nullptr, 64, 256, 1);
  // lnk -> NHWC f16 (T free after conv1)
  nchw2nhwc<<<dim3(256, 16), blk, 0, stream>>>(low_nonkey, T);
  // y = cbr(lnk, w4): X2/X3/Pacc2 dead -> Pacc reusable
  conv_bigK<<<dim3(4, 128, 1), blk, 0, stream>>>(T, wt4, Pacc);
  kreduce<<<1024, blk, 0, stream>>>(Pacc, bn4, Y, 256, 4);
  // z = cbr(x4 - y, w5) -> pooled partials (NO K-split: BN+ReLU nonlinear)
  conv_mfma<<<dim3(64, 4, 1), blk, 0, stream>>>(X1, Y, wt5, bn5, nullptr, nullptr, P, 256, 256, 1);
  // mean -> FC -> FC
  fc_kernel<<<1, 256, 0, stream>>>(P, fw1, fb1, fw2, fb2, (float*)d_out);
}

// Round 16
// 349.716 us; speedup vs baseline: 1.4804x; 1.1326x over previous
//
#include <hip/hip_runtime.h>
#include <math.h>

typedef _Float16 f16;
typedef f16 f16x4 __attribute__((ext_vector_type(4)));
typedef f16 f16x8 __attribute__((ext_vector_type(8)));
typedef float f32x4 __attribute__((ext_vector_type(4)));

#define NB 4

__device__ inline void gload_lds16(const void* g, void* l) {
  __builtin_amdgcn_global_load_lds(
      (const __attribute__((address_space(1))) void*)g,
      (__attribute__((address_space(3))) void*)l, 16, 0, 0);
}

// Mid-conv weights: w[co][ci][9] f32 -> wt[k][co][ci] f16 (conv2/3/5).
__global__ void __launch_bounds__(256)
wtrans_kernel(const float* __restrict__ w, f16* __restrict__ wt, int Co, int Cin) {
  int idx = blockIdx.x * 256 + threadIdx.x;
  int total = Co * Cin * 9;
  if (idx >= total) return;
  int ci = idx % Cin, t2 = idx / Cin;
  int co = t2 % Co, k = t2 / Co;
  wt[idx] = (f16)w[((size_t)co * Cin + ci) * 9 + k];
}

// Big-conv weights: w[co][1024][9] f32 -> wtL[k][cig=128][co=256][8] f16.
// 1KB segment (k,cig, 64 contig co x 16B) = one global_load_lds wave-write.
__global__ void __launch_bounds__(256)
wtrans_big(const float* __restrict__ w, f16* __restrict__ wtL) {
  int idx = blockIdx.x * 256 + threadIdx.x;
  if (idx >= 2359296) return;
  int j = idx & 7, co = (idx >> 3) & 255, cig = (idx >> 11) & 127, k = idx >> 18;
  wtL[idx] = (f16)w[((size_t)co * 1024 + cig * 8 + j) * 9 + k];
}

// NCHW f32 -> NHWC f16 with baked bank-swizzle: within each 4-oct (32ci)
// group, logical oct u stored at phys u ^ (((w+1)>>1)&3). conv_big2's linear
// LDS staging + XOR'd reads then hit all 8 bank-slots (conflict-free).
__global__ void __launch_bounds__(256)
nchw2nhwc(const float* __restrict__ in, f16* __restrict__ out) {
  __shared__ f16 s[64][66];
  const int t = threadIdx.x;
  const int bh = blockIdx.x, c0 = blockIdx.y * 64;
  const int b = bh >> 6, h = bh & 63;
  const int w = t & 63, cr = t >> 6;
  #pragma unroll
  for (int i = 0; i < 16; ++i) {
    int c = c0 + cr * 16 + i;
    s[cr * 16 + i][w] = (f16)in[(((size_t)b * 1024 + c) * 64 + h) * 64 + w];
  }
  __syncthreads();
  #pragma unroll
  for (int i = 0; i < 2; ++i) {
    int task = t + 256 * i;
    int oct = task & 7, w2 = task >> 3;
    f16x8 v;
    #pragma unroll
    for (int j = 0; j < 8; ++j) v[j] = s[oct * 8 + j][w2];
    int sw = ((w2 + 1) >> 1) & 3;
    int po = (oct & 4) | ((oct & 3) ^ sw);
    *(f16x8*)(out + (((size_t)b * 64 + h) * 64 + w2) * 1024 + c0 + po * 8) = v;
  }
}

// conv1/conv4: both operands via global_load_lds, double-buffered, 1 barrier
// per 32-ci chunk. Block 256 thr = 4 waves = 64co x 256px (4 rows); wave =
// 64co x 64px (4m x 4n). xs[2][6][66][32] (swizzled T), ws[2][9][4][64][8]
// (A-reads contiguous 256B/group = conflict-free). blockIdx.x = co-group ->
// one 1.18 MB weight slab per XCD L2. Direct BN+ReLU f16 NHWC out (no Pacc).
__global__ void __launch_bounds__(256, 1)
conv_big2(const f16* __restrict__ in, const f16* __restrict__ wtL,
          const float* __restrict__ bn, f16* __restrict__ out) {
  constexpr int Cin = 1024, Co = 256, NC = 32;
  __shared__ __align__(16) f16 xs[2][6][66][32];
  __shared__ __align__(16) f16 ws[2][9][4][64][8];

  const int t = threadIdx.x;
  const int cog = blockIdx.x;        // 0..3 (fastest-varying -> XCD-clustered)
  const int tile = blockIdx.y;       // 64 = 4b x 16 row-quads
  const int b = tile >> 4;
  const int h0 = (tile & 15) * 4;
  const int co_blk = cog * 64;
  const int wid = t >> 6, lane = t & 63;
  const int l15 = lane & 15, lg = lane >> 4;

  f32x4 acc[4][4];
  #pragma unroll
  for (int m = 0; m < 4; ++m)
    #pragma unroll
    for (int n = 0; n < 4; ++n)
      #pragma unroll
      for (int r = 0; r < 4; ++r) acc[m][n][r] = 0.f;

  const f16* inb = in + (size_t)b * Cin * 4096;

  // zero all of xs once (halo cols 0/65 + OOB rows stay zero forever)
  {
    f16x8 z = {};
    for (int i = t; i < 3168; i += 256) *(f16x8*)((f16*)xs + (size_t)i * 8) = z;
  }

  const int wq = wid;                // each wave owns col-stripe / oct = wid
  const int wS = wq * 16 + (lane >> 2);
  const int octS = lane & 3;

  auto stage = [&](int c, int bu) {
    #pragma unroll
    for (int r = 0; r < 6; ++r) {    // xs: 6 rows x this wave's 16-col stripe
      int gh = h0 - 1 + r;
      if ((unsigned)gh < 64u)
        gload_lds16(inb + ((size_t)gh * 64 + wS) * Cin + c * 32 + octS * 8,
                    &xs[bu][r][1 + wq * 16][0]);
    }
    #pragma unroll
    for (int k = 0; k < 9; ++k)      // ws: 9 taps x this wave's oct
      gload_lds16(wtL + (((size_t)k * 128 + c * 4 + wq) * 256 + co_blk + lane) * 8,
                  &ws[bu][k][wq][0][0]);
  };

  __syncthreads();                   // zeroing visible before DMA writes
  stage(0, 0);
  __syncthreads();                   // drain vmcnt -> chunk 0 ready

  for (int c = 0; c < NC; ++c) {
    const int bu = c & 1;
    if (c + 1 < NC) stage(c + 1, bu ^ 1);   // DMA flies during MFMA phase
    #pragma unroll
    for (int tap = 0; tap < 9; ++tap) {
      const int dh = tap / 3 - 1, dw = tap % 3 - 1;
      f16x8 af[4];
      #pragma unroll
      for (int m = 0; m < 4; ++m)
        af[m] = *(const f16x8*)&ws[bu][tap][lg][m * 16 + l15][0];
      #pragma unroll
      for (int n = 0; n < 4; ++n) {
        const int col = n * 16 + l15 + 1 + dw;
        const int u = lg ^ ((col >> 1) & 3);   // un-swizzle (matches nchw2nhwc)
        const f16x8 bf = *(const f16x8*)&xs[bu][wid + dh + 1][col][u * 8];
        #pragma unroll
        for (int m = 0; m < 4; ++m)
          acc[m][n] = __builtin_amdgcn_mfma_f32_16x16x32_f16(af[m], bf, acc[m][n], 0, 0, 0);
      }
    }
    __syncthreads();                 // reads of bu done + next DMA drained
  }

  // BN + ReLU -> NHWC f16 (standard, unswizzled)
  #pragma unroll
  for (int m = 0; m < 4; ++m) {
    float sc[4], sh[4];
    #pragma unroll
    for (int reg = 0; reg < 4; ++reg) {
      int co = co_blk + m * 16 + lg * 4 + reg;
      sc[reg] = bn[co] / sqrtf(bn[3 * Co + co] + 1e-5f);
      sh[reg] = bn[Co + co] - bn[2 * Co + co] * sc[reg];
    }
    #pragma unroll
    for (int n = 0; n < 4; ++n) {
      f16x4 v;
      #pragma unroll
      for (int reg = 0; reg < 4; ++reg)
        v[reg] = (f16)fmaxf(fmaf(acc[m][n][reg], sc[reg], sh[reg]), 0.f);
      *(f16x4*)(out + ((size_t)(b * 64 + h0 + wid) * 64 + n * 16 + l15) * Co
                    + co_blk + m * 16 + lg * 4) = v;
    }
  }
}

// Mid-size convs (conv2/3/5): both operands in LDS, wave 64co x 64px (4x4).
// kspl via blockIdx.z: pacc!=null -> raw accs (linear). out!=null -> BN+ReLU
// f16 NHWC. Neither -> pooled partials (conv5, kspl MUST be 1: nonlinear).
__global__ void __launch_bounds__(256, 1)
conv_mfma(const f16* __restrict__ in, const f16* __restrict__ in2,
          const f16* __restrict__ wt, const float* __restrict__ bn,
          f16* __restrict__ out, float* __restrict__ pacc,
          float* __restrict__ partial, int Cin, int Co, int kspl) {
  __shared__ __align__(16) f16 xs[6][66][40];
  __shared__ __align__(16) f16 ws[9][64][40];
  __shared__ float s_red[4][64];

  const int t = threadIdx.x;
  const int tile = blockIdx.x;       // 64 = 4b x 16 row-quads
  const int b = tile >> 4;
  const int h0 = (tile & 15) * 4;
  const int co_blk = blockIdx.y * 64;
  const int ciBase = blockIdx.z * (Cin / kspl);
  const int NC = (Cin / kspl) >> 5;
  const int wid = t >> 6, lane = t & 63;
  const int l15 = lane & 15, lg = lane >> 4;
  const int koff = lg * 8;

  f32x4 acc[4][4];
  #pragma unroll
  for (int m = 0; m < 4; ++m)
    #pragma unroll
    for (int n = 0; n < 4; ++n)
      #pragma unroll
      for (int r = 0; r < 4; ++r) acc[m][n][r] = 0.f;

  const f16* inb = in + (size_t)b * Cin * 4096;
  const f16* inb2 = in2 ? in2 + (size_t)b * Cin * 4096 : nullptr;

  const int wS = t >> 2, octS = t & 3;
  f16x8 ireg[6], wreg[9];

  auto load_stage = [&](int ci0) {
    #pragma unroll
    for (int r = 0; r < 6; ++r) {
      int gh = h0 - 1 + r;
      f16x8 v = {};
      if ((unsigned)gh < 64u) {
        size_t off = ((size_t)gh * 64 + wS) * Cin + ci0 + octS * 8;
        v = *(const f16x8*)(inb + off);
        if (inb2) { f16x8 v2 = *(const f16x8*)(inb2 + off); v = v - v2; }
      }
      ireg[r] = v;
    }
    #pragma unroll
    for (int i = 0; i < 9; ++i) {
      int s = t + 256 * i;
      int oct = s & 3, co = (s >> 2) & 63, k = s >> 8;
      wreg[i] = *(const f16x8*)(wt + ((size_t)k * Co + co_blk + co) * Cin + ci0 + oct * 8);
    }
  };
  auto write_stage = [&]() {
    #pragma unroll
    for (int r = 0; r < 6; ++r)
      *(f16x8*)&xs[r][wS + 1][octS * 8] = ireg[r];
    #pragma unroll
    for (int i = 0; i < 9; ++i) {
      int s = t + 256 * i;
      int oct = s & 3, co = (s >> 2) & 63, k = s >> 8;
      *(f16x8*)&ws[k][co][oct * 8] = wreg[i];
    }
  };

  if (t < 48) {
    int r = t >> 3, side = (t >> 2) & 1, oc = t & 3;
    f16x8 z = {};
    *(f16x8*)&xs[r][side * 65][oc * 8] = z;
  }
  load_stage(ciBase);
  write_stage();
  __syncthreads();

  for (int c = 0; c < NC; ++c) {
    if (c + 1 < NC) load_stage(ciBase + ((c + 1) << 5));
    #pragma unroll
    for (int tap = 0; tap < 9; ++tap) {
      const int dh = tap / 3 - 1, dw = tap % 3 - 1;
      f16x8 af[4];
      #pragma unroll
      for (int m = 0; m < 4; ++m)
        af[m] = *(const f16x8*)&ws[tap][m * 16 + l15][koff];
      #pragma unroll
      for (int n = 0; n < 4; ++n) {
        const f16x8 bf = *(const f16x8*)&xs[wid + dh + 1][n * 16 + l15 + 1 + dw][koff];
        #pragma unroll
        for (int m = 0; m < 4; ++m)
          acc[m][n] = __builtin_amdgcn_mfma_f32_16x16x32_f16(af[m], bf, acc[m][n], 0, 0, 0);
      }
    }
    __syncthreads();
    if (c + 1 < NC) write_stage();
    __syncthreads();
  }

  if (pacc) {
    float* pb = pacc + (size_t)blockIdx.z * 16384 * Co + (size_t)b * 4096 * Co;
    #pragma unroll
    for (int m = 0; m < 4; ++m)
      #pragma unroll
      for (int n = 0; n < 4; ++n) {
        int px = (h0 + wid) * 64 + n * 16 + l15;
        *(f32x4*)(pb + (size_t)px * Co + co_blk + m * 16 + lg * 4) = acc[m][n];
      }
  } else if (out) {
    #pragma unroll
    for (int m = 0; m < 4; ++m) {
      float sc[4], sh[4];
      #pragma unroll
      for (int reg = 0; reg < 4; ++reg) {
        int co = co_blk + m * 16 + lg * 4 + reg;
        sc[reg] = bn[co] / sqrtf(bn[3 * Co + co] + 1e-5f);
        sh[reg] = bn[Co + co] - bn[2 * Co + co] * sc[reg];
      }
      #pragma unroll
      for (int n = 0; n < 4; ++n) {
        f16x4 v;
        #pragma unroll
        for (int reg = 0; reg < 4; ++reg)
          v[reg] = (f16)fmaxf(fmaf(acc[m][n][reg], sc[reg], sh[reg]), 0.f);
        *(f16x4*)(out + ((size_t)(b * 64 + h0 + wid) * 64 + n * 16 + l15) * Co
                      + co_blk + m * 16 + lg * 4) = v;
      }
    }
  } else {
    #pragma unroll
    for (int m = 0; m < 4; ++m)
      #pragma unroll
      for (int reg = 0; reg < 4; ++reg) {
        int co = co_blk + m * 16 + lg * 4 + reg;
        float sc = bn[co] / sqrtf(bn[3 * Co + co] + 1e-5f);
        float sh = bn[Co + co] - bn[2 * Co + co] * sc;
        float s = 0.f;
        #pragma unroll
        for (int n = 0; n < 4; ++n)
          s += fmaxf(fmaf(acc[m][n][reg], sc, sh), 0.f);
        s += __shfl_xor(s, 1, 64);
        s += __shfl_xor(s, 2, 64);
        s += __shfl_xor(s, 4, 64);
        s += __shfl_xor(s, 8, 64);
        if (l15 == 0) s_red[wid][m * 16 + lg * 4 + reg] = s;
      }
    __syncthreads();
    if (t < 64) {
      float v = s_red[0][t] + s_red[1][t] + s_red[2][t] + s_red[3][t];
      partial[((size_t)b * Co + co_blk + t) * 16 + (tile & 15)] = v;
    }
  }
}

// Sum nslab K-slices + BN + ReLU -> NHWC f16 (conv2 path).
__global__ void __launch_bounds__(256)
kreduce(const float* __restrict__ pacc, const float* __restrict__ bn,
        f16* __restrict__ out, int Co, int nslab) {
  const int t = threadIdx.x;
  const size_t slab = (size_t)16384 * Co;
  const int cq = t % (Co >> 2);
  float sc[4], sh[4];
  #pragma unroll
  for (int r = 0; r < 4; ++r) {
    int co = cq * 4 + r;
    sc[r] = bn[co] / sqrtf(bn[3 * Co + co] + 1e-5f);
    sh[r] = bn[Co + co] - bn[2 * Co + co] * sc[r];
  }
  #pragma unroll
  for (int i = 0; i < 4; ++i) {
    size_t idx = (size_t)blockIdx.x * 1024 + i * 256 + t;
    f32x4 a = *(const f32x4*)(pacc + idx * 4);
    for (int s = 1; s < nslab; ++s) {
      f32x4 b2 = *(const f32x4*)(pacc + slab * s + idx * 4);
      #pragma unroll
      for (int r = 0; r < 4; ++r) a[r] += b2[r];
    }
    f16x4 v;
    #pragma unroll
    for (int r = 0; r < 4; ++r)
      v[r] = (f16)fmaxf(fmaf(a[r], sc[r], sh[r]), 0.f);
    *(f16x4*)(out + idx * 4) = v;
  }
}

// out[b,h,w,c] = sum_k atten[b,h,w,k] * x[b,h+dh,w+dw,c], NHWC f16, C=64.
__global__ void __launch_bounds__(256)
weighting_nhwc(const f16* __restrict__ x, const float* __restrict__ atten,
               f16* __restrict__ out) {
  __shared__ float s_a[64 * 81];
  const int h = blockIdx.x, b = blockIdx.y;
  const int t = threadIdx.x;
  for (int idx = t; idx < 64 * 81; idx += 256)
    s_a[idx] = atten[(size_t)((b * 64 + h) * 64) * 81 + idx];
  __syncthreads();

  const int w = t & 63, cg = t >> 6;
  float acc[16];
  #pragma unroll
  for (int j = 0; j < 16; ++j) acc[j] = 0.f;

  for (int dh = -4; dh <= 4; ++dh) {
    int hh = h + dh;
    if ((unsigned)hh >= 64u) continue;
    #pragma unroll
    for (int dw = -4; dw <= 4; ++dw) {
      int ww = w + dw;
      if ((unsigned)ww >= 64u) continue;
      float a = s_a[w * 81 + (dh + 4) * 9 + (dw + 4)];
      const f16* xp = x + (((size_t)b * 64 + hh) * 64 + ww) * 64 + cg * 16;
      f16x8 v0 = *(const f16x8*)xp;
      f16x8 v1 = *(const f16x8*)(xp + 8);
      #pragma unroll
      for (int j = 0; j < 8; ++j) {
        acc[j]     = fmaf(a, (float)v0[j], acc[j]);
        acc[8 + j] = fmaf(a, (float)v1[j], acc[8 + j]);
      }
    }
  }
  f16x8 o0, o1;
  #pragma unroll
  for (int j = 0; j < 8; ++j) { o0[j] = (f16)acc[j]; o1[j] = (f16)acc[8 + j]; }
  f16* op = out + (((size_t)b * 64 + h) * 64 + w) * 64 + cg * 16;
  *(f16x8*)op = o0;
  *(f16x8*)(op + 8) = o1;
}

// partial[4][256][16] -> mean -> FC 256->10 -> 1. One block, wave per b.
__global__ void __launch_bounds__(256)
fc_kernel(const float* __restrict__ partial, const float* __restrict__ fw1,
          const float* __restrict__ fb1, const float* __restrict__ fw2,
          const float* __restrict__ fb2, float* __restrict__ outp) {
  const int t = threadIdx.x;
  const int b = t >> 6, lane = t & 63;
  float pooled[4];
  #pragma unroll
  for (int k = 0; k < 4; ++k) {
    int c = lane + 64 * k;
    float s = 0.f;
    #pragma unroll
    for (int p = 0; p < 16; ++p) s += partial[(size_t)(b * 256 + c) * 16 + p];
    pooled[k] = s * (1.f / 4096.f);
  }
  float o = 0.f;
  for (int i = 0; i < 10; ++i) {
    float d = 0.f;
    #pragma unroll
    for (int k = 0; k < 4; ++k) d += pooled[k] * fw1[i * 256 + lane + 64 * k];
    #pragma unroll
    for (int off = 32; off > 0; off >>= 1) d += __shfl_down(d, off, 64);
    o += (d + fb1[i]) * fw2[i];
  }
  if (lane == 0) outp[b] = o + fb2[0];
}

extern "C" void kernel_launch(void* const* d_in, const int* in_sizes, int n_in,
                              void* d_out, int out_size, void* d_ws, size_t ws_size,
                              hipStream_t stream) {
  const float* low_key    = (const float*)d_in[0];
  const float* low_nonkey = (const float*)d_in[1];
  const float* atten      = (const float*)d_in[2];
  const float* w1 = (const float*)d_in[3];  const float* bn1 = (const float*)d_in[4];
  const float* w2 = (const float*)d_in[5];  const float* bn2 = (const float*)d_in[6];
  const float* w3 = (const float*)d_in[7];  const float* bn3 = (const float*)d_in[8];
  const float* w4 = (const float*)d_in[9];  const float* bn4 = (const float*)d_in[10];
  const float* w5 = (const float*)d_in[11]; const float* bn5 = (const float*)d_in[12];
  const float* fw1 = (const float*)d_in[13]; const float* fb1 = (const float*)d_in[14];
  const float* fw2 = (const float*)d_in[15]; const float* fb2 = (const float*)d_in[16];

  f16* T    = (f16*)d_ws;              // 16,777,216 (swizzled NHWC: lk, then lnk)
  f16* X1   = T + 16777216;            // 4,194,304
  f16* Y    = X1 + 4194304;            // 4,194,304
  f16* wt1  = Y + 4194304;             // 2,359,296 (wtL layout)
  f16* wt2  = wt1 + 2359296;           // 147,456
  f16* wt3  = wt2 + 147456;            // 147,456
  f16* wt4  = wt3 + 147456;            // 2,359,296 (wtL layout)
  f16* wt5  = wt4 + 2359296;           // 589,824
  float* P    = (float*)(wt5 + 589824);   // 16,384 f32
  float* Pacc = P + 16384;                // region reused: X2/X3 + Pacc2 (conv2)
  f16* X2     = (f16*)Pacc;               // 1,048,576 f16
  f16* X3     = X2 + 1048576;             // 1,048,576 f16
  float* Pacc2 = Pacc + 2097152;          // 4 slabs x 1,048,576 f32

  dim3 blk(256);
  wtrans_big<<<9216, blk, 0, stream>>>(w1, wt1);
  wtrans_kernel<<<(64 * 256 * 9 + 255) / 256, blk, 0, stream>>>(w2, wt2, 64, 256);
  wtrans_kernel<<<(256 * 64 * 9 + 255) / 256, blk, 0, stream>>>(w3, wt3, 256, 64);
  wtrans_big<<<9216, blk, 0, stream>>>(w4, wt4);
  wtrans_kernel<<<(256 * 256 * 9 + 255) / 256, blk, 0, stream>>>(w5, wt5, 256, 256);

  // lk -> swizzled NHWC f16
  nchw2nhwc<<<dim3(256, 16), blk, 0, stream>>>(low_key, T);
  // x1 = cbr(lk, w1): global_load_lds dbuf conv, direct out
  conv_big2<<<dim3(4, 64), blk, 0, stream>>>(T, wt1, bn1, X1);
  // x2 = cbr(x1, w2): K-split 4 -> Pacc2 -> kreduce
  conv_mfma<<<dim3(64, 1, 4), blk, 0, stream>>>(X1, nullptr, wt2, bn2, nullptr, Pacc2, nullptr, 256, 64, 4);
  kreduce<<<256, blk, 0, stream>>>(Pacc2, bn2, X2, 64, 4);
  // x3 = weighting(x2)
  weighting_nhwc<<<dim3(64, NB), blk, 0, stream>>>(X2, atten, X3);
  // x4 = cbr(x3, w3)  (writes X1)
  conv_mfma<<<dim3(64, 4, 1), blk, 0, stream>>>(X3, nullptr, wt3, bn3, X1, nullptr, nullptr, 64, 256, 1);
  // lnk -> swizzled NHWC f16 (T free after conv1)
  nchw2nhwc<<<dim3(256, 16), blk, 0, stream>>>(low_nonkey, T);
  // y = cbr(lnk, w4)
  conv_big2<<<dim3(4, 64), blk, 0, stream>>>(T, wt4, bn4, Y);
  // z = cbr(x4 - y, w5) -> pooled partials (NO K-split: BN+ReLU nonlinear)
  conv_mfma<<<dim3(64, 4, 1), blk, 0, stream>>>(X1, Y, wt5, bn5, nullptr, nullptr, P, 256, 256, 1);
  // mean -> FC -> FC
  fc_kernel<<<1, 256, 0, stream>>>(P, fw1, fb1, fw2, fb2, (float*)d_out);
}